// Round 5
// baseline (561.000 us; speedup 1.0000x reference)
//
#include <hip/hip_runtime.h>
#include <hip/hip_bf16.h>
#include <stdint.h>

typedef unsigned short u16;
typedef __attribute__((ext_vector_type(8))) short short8;   // 8 x bf16 (4 VGPRs)
typedef __attribute__((ext_vector_type(4))) float f32x4;
typedef __attribute__((ext_vector_type(4))) unsigned short u16x4;

#define DMODEL 1024
#define SEQ    2048
#define BATCH  4
#define NHEAD  16
#define DH     64
#define NTOK   (BATCH*SEQ)
#define BH     (BATCH*NHEAD)
#define EPS    1e-5f

__device__ __forceinline__ float bf2f(u16 u){
  union { unsigned int u; float f; } x; x.u = ((unsigned int)u)<<16; return x.f;
}
__device__ __forceinline__ u16 f2bf(float f){
  union { float f; unsigned int u; } x; x.f = f;
  unsigned int r = x.u + 0x7FFFu + ((x.u>>16)&1u);
  return (u16)(r>>16);
}
// 8 f32 -> 8 bf16 via packed converts (v_cvt_pk_bf16_f32)
__device__ __forceinline__ void pack_bf16x8(const float* pv, short8& out){
  #pragma unroll
  for (int j=0;j<4;++j){
    union { __hip_bfloat162 h2; unsigned int u; } cv;
    cv.h2 = __float22bfloat162_rn(make_float2(pv[2*j], pv[2*j+1]));
    out[2*j]   = (short)(cv.u & 0xFFFFu);
    out[2*j+1] = (short)(cv.u >> 16);
  }
}

__device__ __forceinline__ void gload_lds16(const void* g, void* l){
  __builtin_amdgcn_global_load_lds((__attribute__((address_space(1))) unsigned int*)g,
                                   (__attribute__((address_space(3))) unsigned int*)l,
                                   16, 0, 0);
}

// swizzle key for 128B-row tiles (8 chunks of 16B per row)
__device__ __forceinline__ int swzkey(int row){ return (row&7) ^ ((row>>3)&7); }

// ---------------- weight fp32 -> bf16 convert ----------------
__global__ __launch_bounds__(256) void cvt_f32_bf16(const float* __restrict__ src,
                                                    u16* __restrict__ dst, int n){
  int i = (blockIdx.x*256 + threadIdx.x)*4;
  if (i < n){
    float4 v = *reinterpret_cast<const float4*>(src + i);
    u16x4 o; o.x = f2bf(v.x); o.y = f2bf(v.y); o.z = f2bf(v.z); o.w = f2bf(v.w);
    *reinterpret_cast<u16x4*>(dst + i) = o;
  }
}

// fp32 -> hi/lo bf16 split
__global__ __launch_bounds__(256) void cvt_split(const float* __restrict__ src,
                                                 u16* __restrict__ hi,
                                                 u16* __restrict__ lo, int n){
  int i = (blockIdx.x*256 + threadIdx.x)*4;
  if (i < n){
    float4 v = *reinterpret_cast<const float4*>(src + i);
    float vv[4] = {v.x, v.y, v.z, v.w};
    u16x4 oh, ol;
    #pragma unroll
    for (int j=0;j<4;++j){
      u16 h = f2bf(vv[j]);
      oh[j] = h;
      ol[j] = f2bf(vv[j] - bf2f(h));
    }
    *reinterpret_cast<u16x4*>(hi + i) = oh;
    *reinterpret_cast<u16x4*>(lo + i) = ol;
  }
}

// ---------------- LayerNorm: writes f32 (opt) + bf16 hi (opt) + bf16 lo (opt) ----------------
__global__ __launch_bounds__(256) void ln_kernel(const float* __restrict__ in0,
                                                 const float* __restrict__ in1,
                                                 const float* __restrict__ sc,
                                                 const float* __restrict__ bi,
                                                 float* __restrict__ of32,
                                                 u16* __restrict__ ohi,
                                                 u16* __restrict__ olo){
  int row = blockIdx.x;
  int t = threadIdx.x;
  size_t base = (size_t)row*DMODEL + t*4;
  float4 v = *reinterpret_cast<const float4*>(in0 + base);
  if (in1){
    float4 a = *reinterpret_cast<const float4*>(in1 + base);
    v.x += a.x; v.y += a.y; v.z += a.z; v.w += a.w;
  }
  float s  = v.x+v.y+v.z+v.w;
  float ss = v.x*v.x+v.y*v.y+v.z*v.z+v.w*v.w;
  #pragma unroll
  for (int m=1;m<64;m<<=1){ s += __shfl_xor(s,m); ss += __shfl_xor(ss,m); }
  __shared__ float rs_[4], rss_[4];
  int w = t>>6, l = t&63;
  if (l==0){ rs_[w]=s; rss_[w]=ss; }
  __syncthreads();
  s  = rs_[0]+rs_[1]+rs_[2]+rs_[3];
  ss = rss_[0]+rss_[1]+rss_[2]+rss_[3];
  float mu  = s * (1.0f/DMODEL);
  float var = ss * (1.0f/DMODEL) - mu*mu;
  var = fmaxf(var, 0.0f);
  float r = rsqrtf(var + EPS);
  float4 g = *reinterpret_cast<const float4*>(sc + t*4);
  float4 b = *reinterpret_cast<const float4*>(bi + t*4);
  float o0 = (v.x-mu)*r*g.x + b.x;
  float o1 = (v.y-mu)*r*g.y + b.y;
  float o2 = (v.z-mu)*r*g.z + b.z;
  float o3 = (v.w-mu)*r*g.w + b.w;
  if (of32){
    float4 ov; ov.x=o0; ov.y=o1; ov.z=o2; ov.w=o3;
    *reinterpret_cast<float4*>(of32 + base) = ov;
  }
  float oo[4] = {o0,o1,o2,o3};
  if (ohi){
    u16x4 ob;
    #pragma unroll
    for (int j=0;j<4;++j) ob[j] = f2bf(oo[j]);
    *reinterpret_cast<u16x4*>(ohi + base) = ob;
    if (olo){
      u16x4 obl;
      #pragma unroll
      for (int j=0;j<4;++j) obl[j] = f2bf(oo[j] - bf2f(ob[j]));
      *reinterpret_cast<u16x4*>(olo + base) = obl;
    }
  }
}

// ---------------- split-precision Q,K GEMM ----------------
__global__ __launch_bounds__(256) void gemm_qk_split(const u16* __restrict__ xnh,
                                                     const u16* __restrict__ xnl,
                                                     const u16* __restrict__ whi,
                                                     const u16* __restrict__ wlo,
                                                     u16* __restrict__ qh, u16* __restrict__ ql,
                                                     u16* __restrict__ kh, u16* __restrict__ kl){
  const int K = DMODEL;
  __shared__ u16 Ah[128*32], Al[128*32], Bh[128*32], Bl[128*32];
  int t = threadIdx.x, l = t&63, w = t>>6;
  int bm = blockIdx.y, bn = blockIdx.x;
  int wr = w>>1, wc = w&1;

  f32x4 acc[4][4];
  #pragma unroll
  for (int m=0;m<4;++m)
    #pragma unroll
    for (int n=0;n<4;++n)
      #pragma unroll
      for (int i=0;i<4;++i) acc[m][n][i] = 0.0f;

  const int nk = K/32;
  for (int kt=0; kt<nk; ++kt){
    int k0 = kt*32;
    __syncthreads();
    #pragma unroll
    for (int i=0;i<2;++i){
      int slot = i*256 + t;
      int row = slot>>2, pc = slot&3;
      int lc = pc ^ (row&3);
      gload_lds16(xnh + (size_t)(bm*128 + row)*K + k0 + lc*8, &Ah[slot*8]);
      gload_lds16(xnl + (size_t)(bm*128 + row)*K + k0 + lc*8, &Al[slot*8]);
      gload_lds16(whi + (size_t)(bn*128 + row)*K + k0 + lc*8, &Bh[slot*8]);
      gload_lds16(wlo + (size_t)(bn*128 + row)*K + k0 + lc*8, &Bl[slot*8]);
    }
    __syncthreads();
    short8 ah[4], al[4], bh[4], bl[4];
    #pragma unroll
    for (int m=0;m<4;++m){
      int row = wr*64 + m*16 + (l&15);
      int cp = (l>>4) ^ (row&3);
      ah[m] = *reinterpret_cast<const short8*>(&Ah[row*32 + cp*8]);
      al[m] = *reinterpret_cast<const short8*>(&Al[row*32 + cp*8]);
    }
    #pragma unroll
    for (int n=0;n<4;++n){
      int row = wc*64 + n*16 + (l&15);
      int cp = (l>>4) ^ (row&3);
      bh[n] = *reinterpret_cast<const short8*>(&Bh[row*32 + cp*8]);
      bl[n] = *reinterpret_cast<const short8*>(&Bl[row*32 + cp*8]);
    }
    __builtin_amdgcn_s_setprio(1);
    #pragma unroll
    for (int m=0;m<4;++m)
      #pragma unroll
      for (int n=0;n<4;++n){
        acc[m][n] = __builtin_amdgcn_mfma_f32_16x16x32_bf16(ah[m], bh[n], acc[m][n], 0,0,0);
        acc[m][n] = __builtin_amdgcn_mfma_f32_16x16x32_bf16(ah[m], bl[n], acc[m][n], 0,0,0);
        acc[m][n] = __builtin_amdgcn_mfma_f32_16x16x32_bf16(al[m], bh[n], acc[m][n], 0,0,0);
      }
    __builtin_amdgcn_s_setprio(0);
  }

  #pragma unroll
  for (int m=0;m<4;++m){
    int row0 = bm*128 + wr*64 + m*16 + ((l>>4)<<2);
    #pragma unroll
    for (int n=0;n<4;++n){
      int col = bn*128 + wc*64 + n*16 + (l&15);
      int dg = col & 1023;
      int hh = dg >> 6, dh = dg & 63;
      #pragma unroll
      for (int i=0;i<4;++i){
        int token = row0 + i;
        int bb = token >> 11, s = token & 2047;
        size_t off = ((size_t)(bb*NHEAD + hh)*SEQ + s)*DH + dh;
        float vv = acc[m][n][i];
        u16 hi16 = f2bf(vv);
        u16 lo16 = f2bf(vv - bf2f(hi16));
        if (col < 1024){ qh[off] = hi16; ql[off] = lo16; }
        else           { kh[off] = hi16; kl[off] = lo16; }
      }
    }
  }
}

// ---------------- V transpose: row-major [token][1024] -> vT[bh][64][SEQ] ----------------
__global__ __launch_bounds__(256) void vtrans_kernel(const u16* __restrict__ vrow,
                                                     u16* __restrict__ vT){
  __shared__ u16 tile[64*72];
  int id = blockIdx.x;
  int bh = id>>5, tc = id&31;
  int b = bh >> 4, h = bh & 15;
  int t = threadIdx.x;
  const u16* src = vrow + ((size_t)(b*SEQ) + tc*64)*DMODEL + h*DH;
  #pragma unroll
  for (int i=0;i<2;++i){
    int slot = i*256+t; int row = slot>>3, c = slot&7;
    *reinterpret_cast<short8*>(&tile[row*72 + c*8]) =
        *reinterpret_cast<const short8*>(src + (size_t)row*DMODEL + c*8);
  }
  __syncthreads();
  u16* dst = vT + (size_t)bh*DH*SEQ;
  #pragma unroll
  for (int i=0;i<2;++i){
    int oslot = i*256+t; int d = oslot>>3, tch = oslot&7;
    short8 o;
    #pragma unroll
    for (int j=0;j<8;++j) o[j] = (short)tile[(tch*8+j)*72 + d];
    *reinterpret_cast<short8*>(dst + (size_t)d*SEQ + tc*64 + tch*8) = o;
  }
}

// ---------------- bf16 GEMM (V projection + FFN) ----------------
template<bool BIAS, bool RELU, bool RES, bool OUTF32>
__global__ __launch_bounds__(256) void gemm_bt(const u16* __restrict__ A,
                                               const u16* __restrict__ W,
                                               const float* __restrict__ bias,
                                               const float* __restrict__ resid,
                                               void* __restrict__ outp,
                                               int M, int N, int K){
  __shared__ u16 As[128*32];
  __shared__ u16 Bs[128*32];
  int t = threadIdx.x, l = t&63, w = t>>6;
  int bm = blockIdx.y, bn = blockIdx.x;
  int wr = w>>1, wc = w&1;
  f32x4 acc[4][4];
  #pragma unroll
  for (int m=0;m<4;++m)
    #pragma unroll
    for (int n=0;n<4;++n)
      #pragma unroll
      for (int i=0;i<4;++i) acc[m][n][i] = 0.0f;

  const int nk = K/32;
  for (int kt=0; kt<nk; ++kt){
    int k0 = kt*32;
    __syncthreads();
    #pragma unroll
    for (int i=0;i<2;++i){
      int idx = i*256 + t;
      int r = idx>>2;
      int cc = (idx&3) ^ (r&3);
      gload_lds16(A + (size_t)(bm*128 + r)*K + k0 + cc*8, &As[idx*8]);
      gload_lds16(W + (size_t)(bn*128 + r)*K + k0 + cc*8, &Bs[idx*8]);
    }
    __syncthreads();
    short8 af[4], bf[4];
    #pragma unroll
    for (int m=0;m<4;++m){
      int row = wr*64 + m*16 + (l&15);
      int cp = (l>>4) ^ (row&3);
      af[m] = *reinterpret_cast<const short8*>(&As[row*32 + cp*8]);
    }
    #pragma unroll
    for (int n=0;n<4;++n){
      int row = wc*64 + n*16 + (l&15);
      int cp = (l>>4) ^ (row&3);
      bf[n] = *reinterpret_cast<const short8*>(&Bs[row*32 + cp*8]);
    }
    __builtin_amdgcn_s_setprio(1);
    #pragma unroll
    for (int m=0;m<4;++m)
      #pragma unroll
      for (int n=0;n<4;++n)
        acc[m][n] = __builtin_amdgcn_mfma_f32_16x16x32_bf16(af[m], bf[n], acc[m][n], 0,0,0);
    __builtin_amdgcn_s_setprio(0);
  }

  #pragma unroll
  for (int m=0;m<4;++m){
    int row0 = bm*128 + wr*64 + m*16 + ((l>>4)<<2);
    #pragma unroll
    for (int n=0;n<4;++n){
      int col = bn*128 + wc*64 + n*16 + (l&15);
      float bv = BIAS ? bias[col] : 0.0f;
      #pragma unroll
      for (int i=0;i<4;++i){
        float vv = acc[m][n][i] + bv;
        if (RELU) vv = fmaxf(vv, 0.0f);
        size_t off = (size_t)(row0+i)*N + col;
        if (RES) vv += resid[off];
        if (OUTF32) ((float*)outp)[off] = vv;
        else        ((u16*)outp)[off] = f2bf(vv);
      }
    }
  }
}

// ---------------- flash attention v4: 8 waves, QBLK=256, defer-max ----------------
// grid: BH*(SEQ/QBLK) = 512 blocks of 512 threads (2 blocks/CU exactly).
// S^T = mfma(A=K, B=Q): lane holds P[q][k] for q=l&15, k=st*16+(l>>4)*4+i.
#define QBLK 256
#define KBLK 64
#define RESC_THR 8.0f

__global__ __launch_bounds__(512, 4) void attn_kernel(const u16* __restrict__ qh,
                                                      const u16* __restrict__ ql,
                                                      const u16* __restrict__ kh,
                                                      const u16* __restrict__ kl,
                                                      const u16* __restrict__ vT,
                                                      float* __restrict__ att){
  int id = blockIdx.x;                      // XCD-aware decode: same bh -> same id&7
  int bh = (id & 7) + ((id >> 6) << 3);
  int qb = (id >> 3) & 7;
  int t = threadIdx.x, l = t&63, w = t>>6;
  int g = l>>4;

  const size_t hbase = (size_t)bh * SEQ * DH;
  const u16* khb = kh + hbase;
  const u16* klb = kl + hbase;
  const u16* vtb = vT + hbase;              // [64][SEQ]
  int q0 = qb*QBLK + w*32;

  // Q fragments (B-operand): lane l&15 = q, k-chunk (l>>4)*8
  short8 qfh[2][2], qfl[2][2];
  #pragma unroll
  for (int qs=0;qs<2;++qs)
    #pragma unroll
    for (int kc=0;kc<2;++kc){
      size_t off = hbase + (size_t)(q0 + qs*16 + (l&15))*DH + kc*32 + (g<<3);
      qfh[qs][kc] = *reinterpret_cast<const short8*>(qh + off);
      qfl[qs][kc] = *reinterpret_cast<const short8*>(ql + off);
    }

  __shared__ u16 Kh2[2][KBLK*64];
  __shared__ u16 Kl2[2][KBLK*64];
  __shared__ u16 Vt2[2][KBLK*64];

  // O^T accumulators: lane holds q=l&15, d = dt*16 + (l>>4)*4 + i
  f32x4 o[2][4];
  #pragma unroll
  for (int qs=0;qs<2;++qs)
    #pragma unroll
    for (int dt=0;dt<4;++dt)
      #pragma unroll
      for (int i=0;i<4;++i) o[qs][dt][i] = 0.0f;
  float m_run[2] = {-3.0e38f, -3.0e38f};
  float l_run[2] = {0.0f, 0.0f};

  // 512 threads: each stages one 16B chunk per array per tile
  #define STAGE(bb, kt)                                                         \
    { int row_ = t>>3, pc_ = t&7;                                               \
      int lc_ = pc_ ^ swzkey(row_);                                             \
      gload_lds16(khb + ((size_t)((kt)*KBLK + row_))*DH + lc_*8, &Kh2[bb][t*8]); \
      gload_lds16(klb + ((size_t)((kt)*KBLK + row_))*DH + lc_*8, &Kl2[bb][t*8]); \
      gload_lds16(vtb + (size_t)row_*SEQ + (kt)*KBLK + lc_*8,    &Vt2[bb][t*8]); }

  STAGE(0, 0);
  int cur = 0;
  const int NT = SEQ/KBLK;
  for (int kt=0; kt<NT; ++kt){
    __syncthreads();                 // vmcnt(0)+barrier: staged tile ready
    if (kt+1 < NT) STAGE(cur^1, kt+1);

    char* KhB = (char*)&Kh2[cur][0];
    char* KlB = (char*)&Kl2[cur][0];
    char* VtB = (char*)&Vt2[cur][0];

    // ---- S^T = K·Q^T (split, 3 MFMAs per chunk) ----
    f32x4 sc[2][4];
    #pragma unroll
    for (int qs=0;qs<2;++qs)
      #pragma unroll
      for (int st=0;st<4;++st)
        #pragma unroll
        for (int i=0;i<4;++i) sc[qs][st][i] = 0.0f;

    #pragma unroll
    for (int kc=0;kc<2;++kc)
      #pragma unroll
      for (int st=0;st<4;++st){
        int rr = st*16 + (l&15);               // k-row
        int pcK = (kc*4 + g) ^ swzkey(rr);
        short8 kfh = *reinterpret_cast<const short8*>(KhB + rr*128 + pcK*16);
        short8 kfl = *reinterpret_cast<const short8*>(KlB + rr*128 + pcK*16);
        __builtin_amdgcn_s_setprio(1);
        #pragma unroll
        for (int qs=0;qs<2;++qs){
          sc[qs][st] = __builtin_amdgcn_mfma_f32_16x16x32_bf16(kfh, qfh[qs][kc], sc[qs][st], 0,0,0);
          sc[qs][st] = __builtin_amdgcn_mfma_f32_16x16x32_bf16(kfl, qfh[qs][kc], sc[qs][st], 0,0,0);
          sc[qs][st] = __builtin_amdgcn_mfma_f32_16x16x32_bf16(kfh, qfl[qs][kc], sc[qs][st], 0,0,0);
        }
        __builtin_amdgcn_s_setprio(0);
      }

    // ---- per-lane online softmax (row q = l&15; partners l^16, l^32) ----
    float mt[2];
    #pragma unroll
    for (int qs=0;qs<2;++qs){
      float m0 = sc[qs][0][0];
      #pragma unroll
      for (int st=0;st<4;++st)
        #pragma unroll
        for (int i=0;i<4;++i) m0 = fmaxf(m0, sc[qs][st][i]);
      m0 = fmaxf(m0, __shfl_xor(m0, 16));
      m0 = fmaxf(m0, __shfl_xor(m0, 32));
      mt[qs] = m0;
    }
    // defer-max: skip O-rescale when per-tile growth <= THR for whole wave
    bool defer = (__all((mt[0] <= m_run[0] + RESC_THR) &&
                        (mt[1] <= m_run[1] + RESC_THR)) != 0);

    short8 pf[2][2];                 // [qs][kc] PV B-fragments
    #pragma unroll
    for (int qs=0;qs<2;++qs){
      float mn = defer ? m_run[qs] : fmaxf(m_run[qs], mt[qs]);
      float pv[16];
      float psum = 0.0f;
      #pragma unroll
      for (int st=0;st<4;++st)
        #pragma unroll
        for (int i=0;i<4;++i){
          float p = __expf(sc[qs][st][i] - mn);
          psum += p;
          pv[st*4+i] = p;
        }
      if (defer){
        l_run[qs] += psum;
      } else {
        float scl = __expf(m_run[qs] - mn);
        m_run[qs] = mn;
        l_run[qs] = l_run[qs]*scl + psum;
        #pragma unroll
        for (int dt=0;dt<4;++dt)
          #pragma unroll
          for (int i=0;i<4;++i) o[qs][dt][i] *= scl;
      }
      pack_bf16x8(&pv[0], pf[qs][0]);
      pack_bf16x8(&pv[8], pf[qs][1]);
    }

    // ---- PV: O^T += V^T · P^T (permuted-k fragments) ----
    #pragma unroll
    for (int kc=0;kc<2;++kc)
      #pragma unroll
      for (int dt=0;dt<4;++dt){
        int vr = dt*16 + (l&15);               // d-row
        int sw = swzkey(vr);
        union { uint2 u2[2]; short8 s8; } cv;
        cv.u2[0] = *reinterpret_cast<const uint2*>(VtB + vr*128 + (((kc*4 +     (g>>1)) ^ sw)<<4) + ((g&1)<<3));
        cv.u2[1] = *reinterpret_cast<const uint2*>(VtB + vr*128 + (((kc*4 + 2 + (g>>1)) ^ sw)<<4) + ((g&1)<<3));
        short8 vf = cv.s8;
        __builtin_amdgcn_s_setprio(1);
        o[0][dt] = __builtin_amdgcn_mfma_f32_16x16x32_bf16(vf, pf[0][kc], o[0][dt], 0,0,0);
        o[1][dt] = __builtin_amdgcn_mfma_f32_16x16x32_bf16(vf, pf[1][kc], o[1][dt], 0,0,0);
        __builtin_amdgcn_s_setprio(0);
      }
    cur ^= 1;
  }

  // epilogue: deferred l reduction + store (float4 per dt)
  int b = bh >> 4, hhd = bh & 15;
  #pragma unroll
  for (int qs=0;qs<2;++qs){
    float lt = l_run[qs];
    lt += __shfl_xor(lt, 16);
    lt += __shfl_xor(lt, 32);
    float inv = 1.0f / lt;
    int token = b*SEQ + q0 + qs*16 + (l&15);
    #pragma unroll
    for (int dt=0;dt<4;++dt){
      float4 ov;
      ov.x = o[qs][dt][0]*inv; ov.y = o[qs][dt][1]*inv;
      ov.z = o[qs][dt][2]*inv; ov.w = o[qs][dt][3]*inv;
      *reinterpret_cast<float4*>(att + (size_t)token*DMODEL + hhd*DH + dt*16 + (g<<2)) = ov;
    }
  }
}

// ---------------- launch ----------------
extern "C" void kernel_launch(void* const* d_in, const int* in_sizes, int n_in,
                              void* d_out, int out_size, void* d_ws, size_t ws_size,
                              hipStream_t stream){
  (void)in_sizes; (void)n_in; (void)out_size; (void)ws_size;
  const float* x    = (const float*)d_in[0];
  const float* Wq   = (const float*)d_in[1];
  const float* Wk   = (const float*)d_in[2];
  const float* Wv   = (const float*)d_in[3];
  const float* W1   = (const float*)d_in[4];
  const float* b1   = (const float*)d_in[5];
  const float* W2   = (const float*)d_in[6];
  const float* b2   = (const float*)d_in[7];
  const float* ln1s = (const float*)d_in[8];
  const float* ln1b = (const float*)d_in[9];
  const float* ln2s = (const float*)d_in[10];
  const float* ln2b = (const float*)d_in[11];

  char* ws = (char*)d_ws;
  float* xn_f32  = (float*)ws;  ws += (size_t)NTOK*DMODEL*4;
  float* att_f32 = (float*)ws;  ws += (size_t)NTOK*DMODEL*4;   // first half aliases xnl
  float* xt_f32  = (float*)ws;  ws += (size_t)NTOK*DMODEL*4;
  u16* xt_bf     = (u16*)ws;    ws += (size_t)NTOK*DMODEL*2;   // aliases vrow (dead after vtrans)
  u16* xnh       = (u16*)ws;    ws += (size_t)NTOK*DMODEL*2;
  u16* vT        = (u16*)ws;    ws += (size_t)NTOK*DMODEL*2;
  u16* qh        = (u16*)ws;    ws += (size_t)NTOK*DMODEL*2;   // aliases h_bf (FFN, after attn)
  u16* ql        = (u16*)ws;    ws += (size_t)NTOK*DMODEL*2;
  u16* kh        = (u16*)ws;    ws += (size_t)NTOK*DMODEL*2;
  u16* kl        = (u16*)ws;    ws += (size_t)NTOK*DMODEL*2;
  u16* whi       = (u16*)ws;    ws += (size_t)2*DMODEL*DMODEL*2;
  u16* wlo       = (u16*)ws;    ws += (size_t)2*DMODEL*DMODEL*2;
  u16* wv_bf     = (u16*)ws;    ws += (size_t)DMODEL*DMODEL*2;
  u16* w1_bf     = (u16*)ws;    ws += (size_t)DMODEL*DMODEL*2;
  u16* w2_bf     = (u16*)ws;    ws += (size_t)DMODEL*DMODEL*2;
  u16* xnl       = (u16*)att_f32;   // dead before attn writes att_f32
  u16* vrow      = xt_bf;           // dead before ln2 writes xt_bf
  u16* h_bf      = qh;              // FFN intermediate, after attn

  const int nW = DMODEL*DMODEL;
  const int cvtBlocks = nW/4/256;
  cvt_split<<<cvtBlocks, 256, 0, stream>>>(Wq, whi,      wlo,      nW);
  cvt_split<<<cvtBlocks, 256, 0, stream>>>(Wk, whi + nW, wlo + nW, nW);
  cvt_f32_bf16<<<cvtBlocks, 256, 0, stream>>>(Wv, wv_bf, nW);
  cvt_f32_bf16<<<cvtBlocks, 256, 0, stream>>>(W1, w1_bf, nW);
  cvt_f32_bf16<<<cvtBlocks, 256, 0, stream>>>(W2, w2_bf, nW);

  ln_kernel<<<NTOK, 256, 0, stream>>>(x, nullptr, ln1s, ln1b, xn_f32, xnh, xnl);

  gemm_qk_split<<<dim3(2*DMODEL/128, NTOK/128), 256, 0, stream>>>(
      xnh, xnl, whi, wlo, qh, ql, kh, kl);

  gemm_bt<false,false,false,false><<<dim3(DMODEL/128, NTOK/128), 256, 0, stream>>>(
      xnh, wv_bf, nullptr, nullptr, vrow, NTOK, DMODEL, DMODEL);

  vtrans_kernel<<<BH*(SEQ/64), 256, 0, stream>>>(vrow, vT);

  attn_kernel<<<BH*(SEQ/QBLK), 512, 0, stream>>>(qh, ql, kh, kl, vT, att_f32);

  ln_kernel<<<NTOK, 256, 0, stream>>>(xn_f32, att_f32, ln2s, ln2b, xt_f32, xt_bf, nullptr);

  gemm_bt<true,true,false,false><<<dim3(DMODEL/128, NTOK/128), 256, 0, stream>>>(
      xt_bf, w1_bf, b1, nullptr, h_bf, NTOK, DMODEL, DMODEL);

  gemm_bt<true,false,true,true><<<dim3(DMODEL/128, NTOK/128), 256, 0, stream>>>(
      h_bf, w2_bf, b2, xt_f32, d_out, NTOK, DMODEL, DMODEL);
}

// Round 6
// 445.976 us; speedup vs baseline: 1.2579x; 1.2579x over previous
//
#include <hip/hip_runtime.h>
#include <hip/hip_bf16.h>
#include <stdint.h>

typedef unsigned short u16;
typedef __attribute__((ext_vector_type(8))) short short8;   // 8 x bf16 (4 VGPRs)
typedef __attribute__((ext_vector_type(4))) float f32x4;
typedef __attribute__((ext_vector_type(4))) unsigned short u16x4;

#define DMODEL 1024
#define SEQ    2048
#define BATCH  4
#define NHEAD  16
#define DH     64
#define NTOK   (BATCH*SEQ)
#define BH     (BATCH*NHEAD)
#define EPS    1e-5f

__device__ __forceinline__ float bf2f(u16 u){
  union { unsigned int u; float f; } x; x.u = ((unsigned int)u)<<16; return x.f;
}
__device__ __forceinline__ u16 f2bf(float f){
  union { float f; unsigned int u; } x; x.f = f;
  unsigned int r = x.u + 0x7FFFu + ((x.u>>16)&1u);
  return (u16)(r>>16);
}
// 8 f32 -> 8 bf16 via packed converts (v_cvt_pk_bf16_f32)
__device__ __forceinline__ void pack_bf16x8(const float* pv, short8& out){
  #pragma unroll
  for (int j=0;j<4;++j){
    union { __hip_bfloat162 h2; unsigned int u; } cv;
    cv.h2 = __float22bfloat162_rn(make_float2(pv[2*j], pv[2*j+1]));
    out[2*j]   = (short)(cv.u & 0xFFFFu);
    out[2*j+1] = (short)(cv.u >> 16);
  }
}

__device__ __forceinline__ void gload_lds16(const void* g, void* l){
  __builtin_amdgcn_global_load_lds((__attribute__((address_space(1))) unsigned int*)g,
                                   (__attribute__((address_space(3))) unsigned int*)l,
                                   16, 0, 0);
}

// swizzle key for 128B-row tiles (8 chunks of 16B per row)
__device__ __forceinline__ int swzkey(int row){ return (row&7) ^ ((row>>3)&7); }

// ---------------- weight fp32 -> bf16 convert ----------------
__global__ __launch_bounds__(256) void cvt_f32_bf16(const float* __restrict__ src,
                                                    u16* __restrict__ dst, int n){
  int i = (blockIdx.x*256 + threadIdx.x)*4;
  if (i < n){
    float4 v = *reinterpret_cast<const float4*>(src + i);
    u16x4 o; o.x = f2bf(v.x); o.y = f2bf(v.y); o.z = f2bf(v.z); o.w = f2bf(v.w);
    *reinterpret_cast<u16x4*>(dst + i) = o;
  }
}

// fp32 -> hi/lo bf16 split
__global__ __launch_bounds__(256) void cvt_split(const float* __restrict__ src,
                                                 u16* __restrict__ hi,
                                                 u16* __restrict__ lo, int n){
  int i = (blockIdx.x*256 + threadIdx.x)*4;
  if (i < n){
    float4 v = *reinterpret_cast<const float4*>(src + i);
    float vv[4] = {v.x, v.y, v.z, v.w};
    u16x4 oh, ol;
    #pragma unroll
    for (int j=0;j<4;++j){
      u16 h = f2bf(vv[j]);
      oh[j] = h;
      ol[j] = f2bf(vv[j] - bf2f(h));
    }
    *reinterpret_cast<u16x4*>(hi + i) = oh;
    *reinterpret_cast<u16x4*>(lo + i) = ol;
  }
}

// ---------------- LayerNorm: writes f32 (opt) + bf16 hi (opt) + bf16 lo (opt) ----------------
__global__ __launch_bounds__(256) void ln_kernel(const float* __restrict__ in0,
                                                 const float* __restrict__ in1,
                                                 const float* __restrict__ sc,
                                                 const float* __restrict__ bi,
                                                 float* __restrict__ of32,
                                                 u16* __restrict__ ohi,
                                                 u16* __restrict__ olo){
  int row = blockIdx.x;
  int t = threadIdx.x;
  size_t base = (size_t)row*DMODEL + t*4;
  float4 v = *reinterpret_cast<const float4*>(in0 + base);
  if (in1){
    float4 a = *reinterpret_cast<const float4*>(in1 + base);
    v.x += a.x; v.y += a.y; v.z += a.z; v.w += a.w;
  }
  float s  = v.x+v.y+v.z+v.w;
  float ss = v.x*v.x+v.y*v.y+v.z*v.z+v.w*v.w;
  #pragma unroll
  for (int m=1;m<64;m<<=1){ s += __shfl_xor(s,m); ss += __shfl_xor(ss,m); }
  __shared__ float rs_[4], rss_[4];
  int w = t>>6, l = t&63;
  if (l==0){ rs_[w]=s; rss_[w]=ss; }
  __syncthreads();
  s  = rs_[0]+rs_[1]+rs_[2]+rs_[3];
  ss = rss_[0]+rss_[1]+rss_[2]+rss_[3];
  float mu  = s * (1.0f/DMODEL);
  float var = ss * (1.0f/DMODEL) - mu*mu;
  var = fmaxf(var, 0.0f);
  float r = rsqrtf(var + EPS);
  float4 g = *reinterpret_cast<const float4*>(sc + t*4);
  float4 b = *reinterpret_cast<const float4*>(bi + t*4);
  float o0 = (v.x-mu)*r*g.x + b.x;
  float o1 = (v.y-mu)*r*g.y + b.y;
  float o2 = (v.z-mu)*r*g.z + b.z;
  float o3 = (v.w-mu)*r*g.w + b.w;
  if (of32){
    float4 ov; ov.x=o0; ov.y=o1; ov.z=o2; ov.w=o3;
    *reinterpret_cast<float4*>(of32 + base) = ov;
  }
  float oo[4] = {o0,o1,o2,o3};
  if (ohi){
    u16x4 ob;
    #pragma unroll
    for (int j=0;j<4;++j) ob[j] = f2bf(oo[j]);
    *reinterpret_cast<u16x4*>(ohi + base) = ob;
    if (olo){
      u16x4 obl;
      #pragma unroll
      for (int j=0;j<4;++j) obl[j] = f2bf(oo[j] - bf2f(ob[j]));
      *reinterpret_cast<u16x4*>(olo + base) = obl;
    }
  }
}

// ---------------- split-precision Q,K GEMM ----------------
__global__ __launch_bounds__(256) void gemm_qk_split(const u16* __restrict__ xnh,
                                                     const u16* __restrict__ xnl,
                                                     const u16* __restrict__ whi,
                                                     const u16* __restrict__ wlo,
                                                     u16* __restrict__ qh, u16* __restrict__ ql,
                                                     u16* __restrict__ kh, u16* __restrict__ kl){
  const int K = DMODEL;
  __shared__ u16 Ah[128*32], Al[128*32], Bh[128*32], Bl[128*32];
  int t = threadIdx.x, l = t&63, w = t>>6;
  int bm = blockIdx.y, bn = blockIdx.x;
  int wr = w>>1, wc = w&1;

  f32x4 acc[4][4];
  #pragma unroll
  for (int m=0;m<4;++m)
    #pragma unroll
    for (int n=0;n<4;++n)
      #pragma unroll
      for (int i=0;i<4;++i) acc[m][n][i] = 0.0f;

  const int nk = K/32;
  for (int kt=0; kt<nk; ++kt){
    int k0 = kt*32;
    __syncthreads();
    #pragma unroll
    for (int i=0;i<2;++i){
      int slot = i*256 + t;
      int row = slot>>2, pc = slot&3;
      int lc = pc ^ (row&3);
      gload_lds16(xnh + (size_t)(bm*128 + row)*K + k0 + lc*8, &Ah[slot*8]);
      gload_lds16(xnl + (size_t)(bm*128 + row)*K + k0 + lc*8, &Al[slot*8]);
      gload_lds16(whi + (size_t)(bn*128 + row)*K + k0 + lc*8, &Bh[slot*8]);
      gload_lds16(wlo + (size_t)(bn*128 + row)*K + k0 + lc*8, &Bl[slot*8]);
    }
    __syncthreads();
    short8 ah[4], al[4], bh[4], bl[4];
    #pragma unroll
    for (int m=0;m<4;++m){
      int row = wr*64 + m*16 + (l&15);
      int cp = (l>>4) ^ (row&3);
      ah[m] = *reinterpret_cast<const short8*>(&Ah[row*32 + cp*8]);
      al[m] = *reinterpret_cast<const short8*>(&Al[row*32 + cp*8]);
    }
    #pragma unroll
    for (int n=0;n<4;++n){
      int row = wc*64 + n*16 + (l&15);
      int cp = (l>>4) ^ (row&3);
      bh[n] = *reinterpret_cast<const short8*>(&Bh[row*32 + cp*8]);
      bl[n] = *reinterpret_cast<const short8*>(&Bl[row*32 + cp*8]);
    }
    __builtin_amdgcn_s_setprio(1);
    #pragma unroll
    for (int m=0;m<4;++m)
      #pragma unroll
      for (int n=0;n<4;++n){
        acc[m][n] = __builtin_amdgcn_mfma_f32_16x16x32_bf16(ah[m], bh[n], acc[m][n], 0,0,0);
        acc[m][n] = __builtin_amdgcn_mfma_f32_16x16x32_bf16(ah[m], bl[n], acc[m][n], 0,0,0);
        acc[m][n] = __builtin_amdgcn_mfma_f32_16x16x32_bf16(al[m], bh[n], acc[m][n], 0,0,0);
      }
    __builtin_amdgcn_s_setprio(0);
  }

  #pragma unroll
  for (int m=0;m<4;++m){
    int row0 = bm*128 + wr*64 + m*16 + ((l>>4)<<2);
    #pragma unroll
    for (int n=0;n<4;++n){
      int col = bn*128 + wc*64 + n*16 + (l&15);
      int dg = col & 1023;
      int hh = dg >> 6, dh = dg & 63;
      #pragma unroll
      for (int i=0;i<4;++i){
        int token = row0 + i;
        int bb = token >> 11, s = token & 2047;
        size_t off = ((size_t)(bb*NHEAD + hh)*SEQ + s)*DH + dh;
        float vv = acc[m][n][i];
        u16 hi16 = f2bf(vv);
        u16 lo16 = f2bf(vv - bf2f(hi16));
        if (col < 1024){ qh[off] = hi16; ql[off] = lo16; }
        else           { kh[off] = hi16; kl[off] = lo16; }
      }
    }
  }
}

// ---------------- V transpose: row-major [token][1024] -> vT[bh][64][SEQ] ----------------
__global__ __launch_bounds__(256) void vtrans_kernel(const u16* __restrict__ vrow,
                                                     u16* __restrict__ vT){
  __shared__ u16 tile[64*72];
  int id = blockIdx.x;
  int bh = id>>5, tc = id&31;
  int b = bh >> 4, h = bh & 15;
  int t = threadIdx.x;
  const u16* src = vrow + ((size_t)(b*SEQ) + tc*64)*DMODEL + h*DH;
  #pragma unroll
  for (int i=0;i<2;++i){
    int slot = i*256+t; int row = slot>>3, c = slot&7;
    *reinterpret_cast<short8*>(&tile[row*72 + c*8]) =
        *reinterpret_cast<const short8*>(src + (size_t)row*DMODEL + c*8);
  }
  __syncthreads();
  u16* dst = vT + (size_t)bh*DH*SEQ;
  #pragma unroll
  for (int i=0;i<2;++i){
    int oslot = i*256+t; int d = oslot>>3, tch = oslot&7;
    short8 o;
    #pragma unroll
    for (int j=0;j<8;++j) o[j] = (short)tile[(tch*8+j)*72 + d];
    *reinterpret_cast<short8*>(dst + (size_t)d*SEQ + tc*64 + tch*8) = o;
  }
}

// ---------------- bf16 GEMM (V projection + FFN) ----------------
template<bool BIAS, bool RELU, bool RES, bool OUTF32>
__global__ __launch_bounds__(256) void gemm_bt(const u16* __restrict__ A,
                                               const u16* __restrict__ W,
                                               const float* __restrict__ bias,
                                               const float* __restrict__ resid,
                                               void* __restrict__ outp,
                                               int M, int N, int K){
  __shared__ u16 As[128*32];
  __shared__ u16 Bs[128*32];
  int t = threadIdx.x, l = t&63, w = t>>6;
  int bm = blockIdx.y, bn = blockIdx.x;
  int wr = w>>1, wc = w&1;
  f32x4 acc[4][4];
  #pragma unroll
  for (int m=0;m<4;++m)
    #pragma unroll
    for (int n=0;n<4;++n)
      #pragma unroll
      for (int i=0;i<4;++i) acc[m][n][i] = 0.0f;

  const int nk = K/32;
  for (int kt=0; kt<nk; ++kt){
    int k0 = kt*32;
    __syncthreads();
    #pragma unroll
    for (int i=0;i<2;++i){
      int idx = i*256 + t;
      int r = idx>>2;
      int cc = (idx&3) ^ (r&3);
      gload_lds16(A + (size_t)(bm*128 + r)*K + k0 + cc*8, &As[idx*8]);
      gload_lds16(W + (size_t)(bn*128 + r)*K + k0 + cc*8, &Bs[idx*8]);
    }
    __syncthreads();
    short8 af[4], bf[4];
    #pragma unroll
    for (int m=0;m<4;++m){
      int row = wr*64 + m*16 + (l&15);
      int cp = (l>>4) ^ (row&3);
      af[m] = *reinterpret_cast<const short8*>(&As[row*32 + cp*8]);
    }
    #pragma unroll
    for (int n=0;n<4;++n){
      int row = wc*64 + n*16 + (l&15);
      int cp = (l>>4) ^ (row&3);
      bf[n] = *reinterpret_cast<const short8*>(&Bs[row*32 + cp*8]);
    }
    __builtin_amdgcn_s_setprio(1);
    #pragma unroll
    for (int m=0;m<4;++m)
      #pragma unroll
      for (int n=0;n<4;++n)
        acc[m][n] = __builtin_amdgcn_mfma_f32_16x16x32_bf16(af[m], bf[n], acc[m][n], 0,0,0);
    __builtin_amdgcn_s_setprio(0);
  }

  #pragma unroll
  for (int m=0;m<4;++m){
    int row0 = bm*128 + wr*64 + m*16 + ((l>>4)<<2);
    #pragma unroll
    for (int n=0;n<4;++n){
      int col = bn*128 + wc*64 + n*16 + (l&15);
      float bv = BIAS ? bias[col] : 0.0f;
      #pragma unroll
      for (int i=0;i<4;++i){
        float vv = acc[m][n][i] + bv;
        if (RELU) vv = fmaxf(vv, 0.0f);
        size_t off = (size_t)(row0+i)*N + col;
        if (RES) vv += resid[off];
        if (OUTF32) ((float*)outp)[off] = vv;
        else        ((u16*)outp)[off] = f2bf(vv);
      }
    }
  }
}

// ---------------- flash attention v4b: 8 waves, QBLK=256, defer-max ----------------
// grid: BH*(SEQ/QBLK) = 512 blocks of 512 threads (2 blocks/CU exactly).
// __launch_bounds__(512,2): 256-reg/wave budget -> no spill (r5 lesson: (512,4)
// capped at 128 unified regs; 64 AGPR accumulators forced Q-frag spill, FETCH x11).
#define QBLK 256
#define KBLK 64
#define RESC_THR 8.0f

__global__ __launch_bounds__(512, 2) void attn_kernel(const u16* __restrict__ qh,
                                                      const u16* __restrict__ ql,
                                                      const u16* __restrict__ kh,
                                                      const u16* __restrict__ kl,
                                                      const u16* __restrict__ vT,
                                                      float* __restrict__ att){
  int id = blockIdx.x;                      // XCD-aware decode: same bh -> same id&7
  int bh = (id & 7) + ((id >> 6) << 3);
  int qb = (id >> 3) & 7;
  int t = threadIdx.x, l = t&63, w = t>>6;
  int g = l>>4;

  const size_t hbase = (size_t)bh * SEQ * DH;
  const u16* khb = kh + hbase;
  const u16* klb = kl + hbase;
  const u16* vtb = vT + hbase;              // [64][SEQ]
  int q0 = qb*QBLK + w*32;

  // Q fragments (B-operand): lane l&15 = q, k-chunk (l>>4)*8
  short8 qfh[2][2], qfl[2][2];
  #pragma unroll
  for (int qs=0;qs<2;++qs)
    #pragma unroll
    for (int kc=0;kc<2;++kc){
      size_t off = hbase + (size_t)(q0 + qs*16 + (l&15))*DH + kc*32 + (g<<3);
      qfh[qs][kc] = *reinterpret_cast<const short8*>(qh + off);
      qfl[qs][kc] = *reinterpret_cast<const short8*>(ql + off);
    }

  __shared__ u16 Kh2[2][KBLK*64];
  __shared__ u16 Kl2[2][KBLK*64];
  __shared__ u16 Vt2[2][KBLK*64];

  // O^T accumulators: lane holds q=l&15, d = dt*16 + (l>>4)*4 + i
  f32x4 o[2][4];
  #pragma unroll
  for (int qs=0;qs<2;++qs)
    #pragma unroll
    for (int dt=0;dt<4;++dt)
      #pragma unroll
      for (int i=0;i<4;++i) o[qs][dt][i] = 0.0f;
  float m_run[2] = {-3.0e38f, -3.0e38f};
  float l_run[2] = {0.0f, 0.0f};

  // 512 threads: each stages one 16B chunk per array per tile
  #define STAGE(bb, kt)                                                         \
    { int row_ = t>>3, pc_ = t&7;                                               \
      int lc_ = pc_ ^ swzkey(row_);                                             \
      gload_lds16(khb + ((size_t)((kt)*KBLK + row_))*DH + lc_*8, &Kh2[bb][t*8]); \
      gload_lds16(klb + ((size_t)((kt)*KBLK + row_))*DH + lc_*8, &Kl2[bb][t*8]); \
      gload_lds16(vtb + (size_t)row_*SEQ + (kt)*KBLK + lc_*8,    &Vt2[bb][t*8]); }

  STAGE(0, 0);
  int cur = 0;
  const int NT = SEQ/KBLK;
  for (int kt=0; kt<NT; ++kt){
    __syncthreads();                 // vmcnt(0)+barrier: staged tile ready
    if (kt+1 < NT) STAGE(cur^1, kt+1);

    char* KhB = (char*)&Kh2[cur][0];
    char* KlB = (char*)&Kl2[cur][0];
    char* VtB = (char*)&Vt2[cur][0];

    // ---- S^T = K·Q^T (split, 3 MFMAs per chunk) ----
    f32x4 sc[2][4];
    #pragma unroll
    for (int qs=0;qs<2;++qs)
      #pragma unroll
      for (int st=0;st<4;++st)
        #pragma unroll
        for (int i=0;i<4;++i) sc[qs][st][i] = 0.0f;

    #pragma unroll
    for (int kc=0;kc<2;++kc)
      #pragma unroll
      for (int st=0;st<4;++st){
        int rr = st*16 + (l&15);               // k-row
        int pcK = (kc*4 + g) ^ swzkey(rr);
        short8 kfh = *reinterpret_cast<const short8*>(KhB + rr*128 + pcK*16);
        short8 kfl = *reinterpret_cast<const short8*>(KlB + rr*128 + pcK*16);
        __builtin_amdgcn_s_setprio(1);
        #pragma unroll
        for (int qs=0;qs<2;++qs){
          sc[qs][st] = __builtin_amdgcn_mfma_f32_16x16x32_bf16(kfh, qfh[qs][kc], sc[qs][st], 0,0,0);
          sc[qs][st] = __builtin_amdgcn_mfma_f32_16x16x32_bf16(kfl, qfh[qs][kc], sc[qs][st], 0,0,0);
          sc[qs][st] = __builtin_amdgcn_mfma_f32_16x16x32_bf16(kfh, qfl[qs][kc], sc[qs][st], 0,0,0);
        }
        __builtin_amdgcn_s_setprio(0);
      }

    // ---- per-lane online softmax (row q = l&15; partners l^16, l^32) ----
    float mt[2];
    #pragma unroll
    for (int qs=0;qs<2;++qs){
      float m0 = sc[qs][0][0];
      #pragma unroll
      for (int st=0;st<4;++st)
        #pragma unroll
        for (int i=0;i<4;++i) m0 = fmaxf(m0, sc[qs][st][i]);
      m0 = fmaxf(m0, __shfl_xor(m0, 16));
      m0 = fmaxf(m0, __shfl_xor(m0, 32));
      mt[qs] = m0;
    }
    // defer-max: skip O-rescale when per-tile growth <= THR for whole wave
    bool defer = (__all((mt[0] <= m_run[0] + RESC_THR) &&
                        (mt[1] <= m_run[1] + RESC_THR)) != 0);

    short8 pf[2][2];                 // [qs][kc] PV B-fragments
    #pragma unroll
    for (int qs=0;qs<2;++qs){
      float mn = defer ? m_run[qs] : fmaxf(m_run[qs], mt[qs]);
      float pv[16];
      float psum = 0.0f;
      #pragma unroll
      for (int st=0;st<4;++st)
        #pragma unroll
        for (int i=0;i<4;++i){
          float p = __expf(sc[qs][st][i] - mn);
          psum += p;
          pv[st*4+i] = p;
        }
      if (defer){
        l_run[qs] += psum;
      } else {
        float scl = __expf(m_run[qs] - mn);
        m_run[qs] = mn;
        l_run[qs] = l_run[qs]*scl + psum;
        #pragma unroll
        for (int dt=0;dt<4;++dt)
          #pragma unroll
          for (int i=0;i<4;++i) o[qs][dt][i] *= scl;
      }
      pack_bf16x8(&pv[0], pf[qs][0]);
      pack_bf16x8(&pv[8], pf[qs][1]);
    }

    // ---- PV: O^T += V^T · P^T (permuted-k fragments) ----
    #pragma unroll
    for (int kc=0;kc<2;++kc)
      #pragma unroll
      for (int dt=0;dt<4;++dt){
        int vr = dt*16 + (l&15);               // d-row
        int sw = swzkey(vr);
        union { uint2 u2[2]; short8 s8; } cv;
        cv.u2[0] = *reinterpret_cast<const uint2*>(VtB + vr*128 + (((kc*4 +     (g>>1)) ^ sw)<<4) + ((g&1)<<3));
        cv.u2[1] = *reinterpret_cast<const uint2*>(VtB + vr*128 + (((kc*4 + 2 + (g>>1)) ^ sw)<<4) + ((g&1)<<3));
        short8 vf = cv.s8;
        __builtin_amdgcn_s_setprio(1);
        o[0][dt] = __builtin_amdgcn_mfma_f32_16x16x32_bf16(vf, pf[0][kc], o[0][dt], 0,0,0);
        o[1][dt] = __builtin_amdgcn_mfma_f32_16x16x32_bf16(vf, pf[1][kc], o[1][dt], 0,0,0);
        __builtin_amdgcn_s_setprio(0);
      }
    cur ^= 1;
  }

  // epilogue: deferred l reduction + store (float4 per dt)
  int b = bh >> 4, hhd = bh & 15;
  #pragma unroll
  for (int qs=0;qs<2;++qs){
    float lt = l_run[qs];
    lt += __shfl_xor(lt, 16);
    lt += __shfl_xor(lt, 32);
    float inv = 1.0f / lt;
    int token = b*SEQ + q0 + qs*16 + (l&15);
    #pragma unroll
    for (int dt=0;dt<4;++dt){
      float4 ov;
      ov.x = o[qs][dt][0]*inv; ov.y = o[qs][dt][1]*inv;
      ov.z = o[qs][dt][2]*inv; ov.w = o[qs][dt][3]*inv;
      *reinterpret_cast<float4*>(att + (size_t)token*DMODEL + hhd*DH + dt*16 + (g<<2)) = ov;
    }
  }
}

// ---------------- launch ----------------
extern "C" void kernel_launch(void* const* d_in, const int* in_sizes, int n_in,
                              void* d_out, int out_size, void* d_ws, size_t ws_size,
                              hipStream_t stream){
  (void)in_sizes; (void)n_in; (void)out_size; (void)ws_size;
  const float* x    = (const float*)d_in[0];
  const float* Wq   = (const float*)d_in[1];
  const float* Wk   = (const float*)d_in[2];
  const float* Wv   = (const float*)d_in[3];
  const float* W1   = (const float*)d_in[4];
  const float* b1   = (const float*)d_in[5];
  const float* W2   = (const float*)d_in[6];
  const float* b2   = (const float*)d_in[7];
  const float* ln1s = (const float*)d_in[8];
  const float* ln1b = (const float*)d_in[9];
  const float* ln2s = (const float*)d_in[10];
  const float* ln2b = (const float*)d_in[11];

  char* ws = (char*)d_ws;
  float* xn_f32  = (float*)ws;  ws += (size_t)NTOK*DMODEL*4;
  float* att_f32 = (float*)ws;  ws += (size_t)NTOK*DMODEL*4;   // first half aliases xnl
  float* xt_f32  = (float*)ws;  ws += (size_t)NTOK*DMODEL*4;
  u16* xt_bf     = (u16*)ws;    ws += (size_t)NTOK*DMODEL*2;   // aliases vrow (dead after vtrans)
  u16* xnh       = (u16*)ws;    ws += (size_t)NTOK*DMODEL*2;
  u16* vT        = (u16*)ws;    ws += (size_t)NTOK*DMODEL*2;
  u16* qh        = (u16*)ws;    ws += (size_t)NTOK*DMODEL*2;   // aliases h_bf (FFN, after attn)
  u16* ql        = (u16*)ws;    ws += (size_t)NTOK*DMODEL*2;
  u16* kh        = (u16*)ws;    ws += (size_t)NTOK*DMODEL*2;
  u16* kl        = (u16*)ws;    ws += (size_t)NTOK*DMODEL*2;
  u16* whi       = (u16*)ws;    ws += (size_t)2*DMODEL*DMODEL*2;
  u16* wlo       = (u16*)ws;    ws += (size_t)2*DMODEL*DMODEL*2;
  u16* wv_bf     = (u16*)ws;    ws += (size_t)DMODEL*DMODEL*2;
  u16* w1_bf     = (u16*)ws;    ws += (size_t)DMODEL*DMODEL*2;
  u16* w2_bf     = (u16*)ws;    ws += (size_t)DMODEL*DMODEL*2;
  u16* xnl       = (u16*)att_f32;   // dead before attn writes att_f32
  u16* vrow      = xt_bf;           // dead before ln2 writes xt_bf
  u16* h_bf      = qh;              // FFN intermediate, after attn

  const int nW = DMODEL*DMODEL;
  const int cvtBlocks = nW/4/256;
  cvt_split<<<cvtBlocks, 256, 0, stream>>>(Wq, whi,      wlo,      nW);
  cvt_split<<<cvtBlocks, 256, 0, stream>>>(Wk, whi + nW, wlo + nW, nW);
  cvt_f32_bf16<<<cvtBlocks, 256, 0, stream>>>(Wv, wv_bf, nW);
  cvt_f32_bf16<<<cvtBlocks, 256, 0, stream>>>(W1, w1_bf, nW);
  cvt_f32_bf16<<<cvtBlocks, 256, 0, stream>>>(W2, w2_bf, nW);

  ln_kernel<<<NTOK, 256, 0, stream>>>(x, nullptr, ln1s, ln1b, xn_f32, xnh, xnl);

  gemm_qk_split<<<dim3(2*DMODEL/128, NTOK/128), 256, 0, stream>>>(
      xnh, xnl, whi, wlo, qh, ql, kh, kl);

  gemm_bt<false,false,false,false><<<dim3(DMODEL/128, NTOK/128), 256, 0, stream>>>(
      xnh, wv_bf, nullptr, nullptr, vrow, NTOK, DMODEL, DMODEL);

  vtrans_kernel<<<BH*(SEQ/64), 256, 0, stream>>>(vrow, vT);

  attn_kernel<<<BH*(SEQ/QBLK), 512, 0, stream>>>(qh, ql, kh, kl, vT, att_f32);

  ln_kernel<<<NTOK, 256, 0, stream>>>(xn_f32, att_f32, ln2s, ln2b, xt_f32, xt_bf, nullptr);

  gemm_bt<true,true,false,false><<<dim3(DMODEL/128, NTOK/128), 256, 0, stream>>>(
      xt_bf, w1_bf, b1, nullptr, h_bf, NTOK, DMODEL, DMODEL);

  gemm_bt<true,false,true,true><<<dim3(DMODEL/128, NTOK/128), 256, 0, stream>>>(
      h_bf, w2_bf, b2, xt_f32, d_out, NTOK, DMODEL, DMODEL);
}

// Round 7
// 401.443 us; speedup vs baseline: 1.3975x; 1.1109x over previous
//
#include <hip/hip_runtime.h>
#include <stdint.h>

typedef unsigned short u16;
typedef __attribute__((ext_vector_type(8))) short short8;     // 8 x bf16
typedef __attribute__((ext_vector_type(4))) float f32x4;
typedef __attribute__((ext_vector_type(4))) unsigned short u16x4;
typedef _Float16 h16;
typedef __attribute__((ext_vector_type(8))) _Float16 f16x8;   // 8 x fp16
typedef __attribute__((ext_vector_type(4))) _Float16 h16x4;

#define DMODEL 1024
#define SEQ    2048
#define BATCH  4
#define NHEAD  16
#define DH     64
#define NTOK   (BATCH*SEQ)
#define BH     (BATCH*NHEAD)
#define EPS    1e-5f

__device__ __forceinline__ float bf2f(u16 u){
  union { unsigned int u; float f; } x; x.u = ((unsigned int)u)<<16; return x.f;
}
__device__ __forceinline__ u16 f2bf(float f){
  union { float f; unsigned int u; } x; x.f = f;
  unsigned int r = x.u + 0x7FFFu + ((x.u>>16)&1u);
  return (u16)(r>>16);
}

__device__ __forceinline__ void gload_lds16(const void* g, void* l){
  __builtin_amdgcn_global_load_lds((__attribute__((address_space(1))) unsigned int*)g,
                                   (__attribute__((address_space(3))) unsigned int*)l,
                                   16, 0, 0);
}

// swizzle key for 128B-row tiles (8 chunks of 16B per row)
__device__ __forceinline__ int swzkey(int row){ return (row&7) ^ ((row>>3)&7); }

// ---------------- weight prep: Wq,Wk -> bf16 hi/lo; Wv -> bf16; W1,W2 -> fp16 ----------------
__global__ __launch_bounds__(256) void prep_weights(const float* __restrict__ Wq,
                                                    const float* __restrict__ Wk,
                                                    const float* __restrict__ Wv,
                                                    const float* __restrict__ W1,
                                                    const float* __restrict__ W2,
                                                    u16* __restrict__ whi, u16* __restrict__ wlo,
                                                    u16* __restrict__ wvh,
                                                    h16* __restrict__ w1h, h16* __restrict__ w2h){
  const int nW = DMODEL*DMODEL;
  int r = blockIdx.x >> 10;
  int i = ((blockIdx.x & 1023)*256 + threadIdx.x)*4;
  if (r == 0 || r == 1){
    const float* src = (r==0) ? Wq : Wk;
    float4 v = *reinterpret_cast<const float4*>(src + i);
    float vv[4] = {v.x, v.y, v.z, v.w};
    u16x4 oh, ol;
    #pragma unroll
    for (int j=0;j<4;++j){
      u16 h = f2bf(vv[j]);
      oh[j] = h;
      ol[j] = f2bf(vv[j] - bf2f(h));
    }
    *reinterpret_cast<u16x4*>(whi + r*nW + i) = oh;
    *reinterpret_cast<u16x4*>(wlo + r*nW + i) = ol;
  } else if (r == 2){
    float4 v = *reinterpret_cast<const float4*>(Wv + i);
    u16x4 o; o.x=f2bf(v.x); o.y=f2bf(v.y); o.z=f2bf(v.z); o.w=f2bf(v.w);
    *reinterpret_cast<u16x4*>(wvh + i) = o;
  } else {
    const float* src = (r==3) ? W1 : W2;
    h16* dst = (r==3) ? w1h : w2h;
    float4 v = *reinterpret_cast<const float4*>(src + i);
    h16x4 o; o[0]=(h16)v.x; o[1]=(h16)v.y; o[2]=(h16)v.z; o[3]=(h16)v.w;
    *reinterpret_cast<h16x4*>(dst + i) = o;
  }
}

// ---------------- LayerNorm (wave-per-row): f32 (opt) + bf16 hi/lo (opt) + fp16 (opt) ----------------
__global__ __launch_bounds__(256) void ln_kernel(const float* __restrict__ in0,
                                                 const float* __restrict__ in1,
                                                 const float* __restrict__ sc,
                                                 const float* __restrict__ bi,
                                                 float* __restrict__ of32,
                                                 u16* __restrict__ ohi,
                                                 u16* __restrict__ olo,
                                                 h16* __restrict__ oh16){
  int row = blockIdx.x*4 + (threadIdx.x>>6);
  int l = threadIdx.x & 63;
  size_t rbase = (size_t)row*DMODEL;
  float v[16];
  #pragma unroll
  for (int q=0;q<4;++q){
    float4 t = *reinterpret_cast<const float4*>(in0 + rbase + q*256 + l*4);
    if (in1){
      float4 a = *reinterpret_cast<const float4*>(in1 + rbase + q*256 + l*4);
      t.x+=a.x; t.y+=a.y; t.z+=a.z; t.w+=a.w;
    }
    v[q*4]=t.x; v[q*4+1]=t.y; v[q*4+2]=t.z; v[q*4+3]=t.w;
  }
  float s=0.f, ss=0.f;
  #pragma unroll
  for (int j=0;j<16;++j){ s += v[j]; ss += v[j]*v[j]; }
  #pragma unroll
  for (int m=1;m<64;m<<=1){ s += __shfl_xor(s,m); ss += __shfl_xor(ss,m); }
  float mu  = s * (1.0f/DMODEL);
  float var = fmaxf(ss * (1.0f/DMODEL) - mu*mu, 0.0f);
  float r = rsqrtf(var + EPS);
  #pragma unroll
  for (int q=0;q<4;++q){
    float4 g = *reinterpret_cast<const float4*>(sc + q*256 + l*4);
    float4 b = *reinterpret_cast<const float4*>(bi + q*256 + l*4);
    float o0 = (v[q*4  ]-mu)*r*g.x + b.x;
    float o1 = (v[q*4+1]-mu)*r*g.y + b.y;
    float o2 = (v[q*4+2]-mu)*r*g.z + b.z;
    float o3 = (v[q*4+3]-mu)*r*g.w + b.w;
    size_t off = rbase + q*256 + l*4;
    if (of32){
      float4 ov; ov.x=o0; ov.y=o1; ov.z=o2; ov.w=o3;
      *reinterpret_cast<float4*>(of32 + off) = ov;
    }
    if (ohi){
      float oo[4] = {o0,o1,o2,o3};
      u16x4 ob, obl;
      #pragma unroll
      for (int j=0;j<4;++j){
        ob[j] = f2bf(oo[j]);
        obl[j] = f2bf(oo[j] - bf2f(ob[j]));
      }
      *reinterpret_cast<u16x4*>(ohi + off) = ob;
      if (olo) *reinterpret_cast<u16x4*>(olo + off) = obl;
    }
    if (oh16){
      h16x4 oh; oh[0]=(h16)o0; oh[1]=(h16)o1; oh[2]=(h16)o2; oh[3]=(h16)o3;
      *reinterpret_cast<h16x4*>(oh16 + off) = oh;
    }
  }
}

// ---------------- fused QKV GEMM ----------------
// A = xn (bf16 hi/lo), W = [Wq;Wk;Wv]. bn<16: split 3-MFMA (Q,K); bn>=16: 1-MFMA (V).
// Outputs fp16: qT[bh][64][SEQ] (vectorized), k[bh][SEQ][64] (scalar), vT[bh][64][SEQ] (vectorized).
__global__ __launch_bounds__(256) void gemm_qkv(const u16* __restrict__ xnh,
                                                const u16* __restrict__ xnl,
                                                const u16* __restrict__ whi,
                                                const u16* __restrict__ wlo,
                                                const u16* __restrict__ wvh,
                                                h16* __restrict__ qT,
                                                h16* __restrict__ kR,
                                                h16* __restrict__ vT){
  const int K = DMODEL;
  __shared__ u16 Ah[128*32], Al[128*32], Bh[128*32], Bl[128*32];
  int t = threadIdx.x, l = t&63, w = t>>6;
  int bm = blockIdx.y, bn = blockIdx.x;
  int wr = w>>1, wc = w&1;
  const bool splitB = (bn < 16);
  const u16* Bsrc = splitB ? (whi + (size_t)bn*128*K) : (wvh + (size_t)(bn-16)*128*K);

  f32x4 acc[4][4];
  #pragma unroll
  for (int m=0;m<4;++m)
    #pragma unroll
    for (int n=0;n<4;++n)
      #pragma unroll
      for (int i=0;i<4;++i) acc[m][n][i] = 0.0f;

  const int nk = K/32;
  for (int kt=0; kt<nk; ++kt){
    int k0 = kt*32;
    __syncthreads();
    #pragma unroll
    for (int i=0;i<2;++i){
      int slot = i*256 + t;
      int row = slot>>2, pc = slot&3;
      int lc = pc ^ (row&3);
      gload_lds16(xnh + (size_t)(bm*128 + row)*K + k0 + lc*8, &Ah[slot*8]);
      gload_lds16(Bsrc + (size_t)row*K + k0 + lc*8, &Bh[slot*8]);
      if (splitB){
        gload_lds16(xnl + (size_t)(bm*128 + row)*K + k0 + lc*8, &Al[slot*8]);
        gload_lds16(wlo + (size_t)bn*128*K + (size_t)row*K + k0 + lc*8, &Bl[slot*8]);
      }
    }
    __syncthreads();
    short8 ah[4], al[4], bh[4], bl[4];
    #pragma unroll
    for (int m=0;m<4;++m){
      int row = wr*64 + m*16 + (l&15);
      int cp = (l>>4) ^ (row&3);
      ah[m] = *reinterpret_cast<const short8*>(&Ah[row*32 + cp*8]);
      if (splitB) al[m] = *reinterpret_cast<const short8*>(&Al[row*32 + cp*8]);
    }
    #pragma unroll
    for (int n=0;n<4;++n){
      int row = wc*64 + n*16 + (l&15);
      int cp = (l>>4) ^ (row&3);
      bh[n] = *reinterpret_cast<const short8*>(&Bh[row*32 + cp*8]);
      if (splitB) bl[n] = *reinterpret_cast<const short8*>(&Bl[row*32 + cp*8]);
    }
    __builtin_amdgcn_s_setprio(1);
    if (splitB){
      #pragma unroll
      for (int m=0;m<4;++m)
        #pragma unroll
        for (int n=0;n<4;++n){
          acc[m][n] = __builtin_amdgcn_mfma_f32_16x16x32_bf16(ah[m], bh[n], acc[m][n], 0,0,0);
          acc[m][n] = __builtin_amdgcn_mfma_f32_16x16x32_bf16(ah[m], bl[n], acc[m][n], 0,0,0);
          acc[m][n] = __builtin_amdgcn_mfma_f32_16x16x32_bf16(al[m], bh[n], acc[m][n], 0,0,0);
        }
    } else {
      #pragma unroll
      for (int m=0;m<4;++m)
        #pragma unroll
        for (int n=0;n<4;++n)
          acc[m][n] = __builtin_amdgcn_mfma_f32_16x16x32_bf16(ah[m], bh[n], acc[m][n], 0,0,0);
    }
    __builtin_amdgcn_s_setprio(0);
  }

  // epilogue
  const bool isK = (bn >= 8 && bn < 16);
  #pragma unroll
  for (int m=0;m<4;++m){
    int row0 = bm*128 + wr*64 + m*16 + ((l>>4)<<2);
    int b = row0 >> 11, s0 = row0 & 2047;
    #pragma unroll
    for (int n=0;n<4;++n){
      int col = bn*128 + wc*64 + n*16 + (l&15);
      int dg = col & 1023;
      int hh = dg >> 6, dh = dg & 63;
      if (isK){
        #pragma unroll
        for (int i=0;i<4;++i)
          kR[((size_t)(b*NHEAD + hh)*SEQ + s0 + i)*DH + dh] = (h16)acc[m][n][i];
      } else {
        h16x4 ov;
        #pragma unroll
        for (int i=0;i<4;++i) ov[i] = (h16)acc[m][n][i];
        h16* dst = ((col < 1024) ? qT : vT) + ((size_t)(b*NHEAD + hh)*DH + dh)*SEQ + s0;
        *reinterpret_cast<h16x4*>(dst) = ov;
      }
    }
  }
}

// ---------------- fp16 GEMM (FFN) ----------------
template<bool RELU, bool RES, bool OUTF32>
__global__ __launch_bounds__(256) void gemm_ffn(const h16* __restrict__ A,
                                                const h16* __restrict__ W,
                                                const float* __restrict__ bias,
                                                const float* __restrict__ resid,
                                                void* __restrict__ outp,
                                                int M, int N, int K){
  __shared__ h16 As[128*32];
  __shared__ h16 Bs[128*32];
  int t = threadIdx.x, l = t&63, w = t>>6;
  int bm = blockIdx.y, bn = blockIdx.x;
  int wr = w>>1, wc = w&1;
  f32x4 acc[4][4];
  #pragma unroll
  for (int m=0;m<4;++m)
    #pragma unroll
    for (int n=0;n<4;++n)
      #pragma unroll
      for (int i=0;i<4;++i) acc[m][n][i] = 0.0f;

  const int nk = K/32;
  for (int kt=0; kt<nk; ++kt){
    int k0 = kt*32;
    __syncthreads();
    #pragma unroll
    for (int i=0;i<2;++i){
      int idx = i*256 + t;
      int r = idx>>2;
      int cc = (idx&3) ^ (r&3);
      gload_lds16(A + (size_t)(bm*128 + r)*K + k0 + cc*8, &As[idx*8]);
      gload_lds16(W + (size_t)(bn*128 + r)*K + k0 + cc*8, &Bs[idx*8]);
    }
    __syncthreads();
    f16x8 af[4], bf[4];
    #pragma unroll
    for (int m=0;m<4;++m){
      int row = wr*64 + m*16 + (l&15);
      int cp = (l>>4) ^ (row&3);
      af[m] = *reinterpret_cast<const f16x8*>(&As[row*32 + cp*8]);
    }
    #pragma unroll
    for (int n=0;n<4;++n){
      int row = wc*64 + n*16 + (l&15);
      int cp = (l>>4) ^ (row&3);
      bf[n] = *reinterpret_cast<const f16x8*>(&Bs[row*32 + cp*8]);
    }
    __builtin_amdgcn_s_setprio(1);
    #pragma unroll
    for (int m=0;m<4;++m)
      #pragma unroll
      for (int n=0;n<4;++n)
        acc[m][n] = __builtin_amdgcn_mfma_f32_16x16x32_f16(af[m], bf[n], acc[m][n], 0,0,0);
    __builtin_amdgcn_s_setprio(0);
  }

  #pragma unroll
  for (int m=0;m<4;++m){
    int row0 = bm*128 + wr*64 + m*16 + ((l>>4)<<2);
    #pragma unroll
    for (int n=0;n<4;++n){
      int col = bn*128 + wc*64 + n*16 + (l&15);
      float bv = bias[col];
      #pragma unroll
      for (int i=0;i<4;++i){
        float vv = acc[m][n][i] + bv;
        if (RELU) vv = fmaxf(vv, 0.0f);
        size_t off = (size_t)(row0+i)*N + col;
        if (RES) vv += resid[off];
        if (OUTF32) ((float*)outp)[off] = vv;
        else        ((h16*)outp)[off] = (h16)vv;
      }
    }
  }
}

// ---------------- flash attention v5: fp16, 8 waves, QBLK=256, defer-max ----------------
#define QBLK 256
#define KBLK 64
#define RESC_THR 8.0f

__global__ __launch_bounds__(512, 2) void attn_kernel(const h16* __restrict__ qT,
                                                      const h16* __restrict__ kR,
                                                      const h16* __restrict__ vT,
                                                      float* __restrict__ att){
  int id = blockIdx.x;                      // XCD-aware decode: same bh -> same id&7
  int bh = (id & 7) + ((id >> 6) << 3);
  int qb = (id >> 3) & 7;
  int t = threadIdx.x, l = t&63, w = t>>6;
  int g = l>>4;

  const size_t hbase = (size_t)bh * SEQ * DH;
  const h16* khb = kR + hbase;              // [s][64]
  const h16* qtb = qT + hbase;              // [64][s]
  const h16* vtb = vT + hbase;              // [64][s]
  int q0 = qb*QBLK + w*32;

  // Q fragments from qT (strided scalar loads, once per block)
  f16x8 qf[2][2];
  #pragma unroll
  for (int qs=0;qs<2;++qs)
    #pragma unroll
    for (int kc=0;kc<2;++kc){
      #pragma unroll
      for (int j=0;j<8;++j)
        qf[qs][kc][j] = qtb[(size_t)(kc*32 + g*8 + j)*SEQ + q0 + qs*16 + (l&15)];
    }

  __shared__ h16 Kh2[2][KBLK*64];
  __shared__ h16 Vt2[2][KBLK*64];

  // O^T accumulators: lane holds q=l&15, d = dt*16 + (l>>4)*4 + i
  f32x4 o[2][4];
  #pragma unroll
  for (int qs=0;qs<2;++qs)
    #pragma unroll
    for (int dt=0;dt<4;++dt)
      #pragma unroll
      for (int i=0;i<4;++i) o[qs][dt][i] = 0.0f;
  float m_run[2] = {-3.0e38f, -3.0e38f};
  float l_run[2] = {0.0f, 0.0f};

  // 512 threads: one 16B chunk per array per tile
  #define STAGE(bb, kt)                                                          \
    { int row_ = t>>3, pc_ = t&7;                                                \
      int lc_ = pc_ ^ swzkey(row_);                                              \
      gload_lds16(khb + ((size_t)((kt)*KBLK + row_))*DH + lc_*8, &Kh2[bb][t*8]); \
      gload_lds16(vtb + (size_t)row_*SEQ + (kt)*KBLK + lc_*8,    &Vt2[bb][t*8]); }

  STAGE(0, 0);
  int cur = 0;
  const int NT = SEQ/KBLK;
  for (int kt=0; kt<NT; ++kt){
    __syncthreads();                 // vmcnt(0)+barrier: staged tile ready
    if (kt+1 < NT) STAGE(cur^1, kt+1);

    char* KhB = (char*)&Kh2[cur][0];
    char* VtB = (char*)&Vt2[cur][0];

    // ---- S^T = K·Q^T (fp16, 1 MFMA per chunk) ----
    f32x4 sc[2][4];
    #pragma unroll
    for (int qs=0;qs<2;++qs)
      #pragma unroll
      for (int st=0;st<4;++st)
        #pragma unroll
        for (int i=0;i<4;++i) sc[qs][st][i] = 0.0f;

    #pragma unroll
    for (int kc=0;kc<2;++kc)
      #pragma unroll
      for (int st=0;st<4;++st){
        int rr = st*16 + (l&15);               // k-row
        int pcK = (kc*4 + g) ^ swzkey(rr);
        f16x8 kf = *reinterpret_cast<const f16x8*>(KhB + rr*128 + pcK*16);
        __builtin_amdgcn_s_setprio(1);
        sc[0][st] = __builtin_amdgcn_mfma_f32_16x16x32_f16(kf, qf[0][kc], sc[0][st], 0,0,0);
        sc[1][st] = __builtin_amdgcn_mfma_f32_16x16x32_f16(kf, qf[1][kc], sc[1][st], 0,0,0);
        __builtin_amdgcn_s_setprio(0);
      }

    // ---- per-lane online softmax (row q = l&15; partners l^16, l^32) ----
    float mt[2];
    #pragma unroll
    for (int qs=0;qs<2;++qs){
      float m0 = sc[qs][0][0];
      #pragma unroll
      for (int st=0;st<4;++st)
        #pragma unroll
        for (int i=0;i<4;++i) m0 = fmaxf(m0, sc[qs][st][i]);
      m0 = fmaxf(m0, __shfl_xor(m0, 16));
      m0 = fmaxf(m0, __shfl_xor(m0, 32));
      mt[qs] = m0;
    }
    bool defer = (__all((mt[0] <= m_run[0] + RESC_THR) &&
                        (mt[1] <= m_run[1] + RESC_THR)) != 0);

    f16x8 pf[2][2];                 // [qs][kc] PV B-fragments
    #pragma unroll
    for (int qs=0;qs<2;++qs){
      float mn = defer ? m_run[qs] : fmaxf(m_run[qs], mt[qs]);
      float pv[16];
      float psum = 0.0f;
      #pragma unroll
      for (int st=0;st<4;++st)
        #pragma unroll
        for (int i=0;i<4;++i){
          float p = __expf(sc[qs][st][i] - mn);
          psum += p;
          pv[st*4+i] = p;
        }
      if (defer){
        l_run[qs] += psum;
      } else {
        float scl = __expf(m_run[qs] - mn);
        m_run[qs] = mn;
        l_run[qs] = l_run[qs]*scl + psum;
        #pragma unroll
        for (int dt=0;dt<4;++dt)
          #pragma unroll
          for (int i=0;i<4;++i) o[qs][dt][i] *= scl;
      }
      #pragma unroll
      for (int kc=0;kc<2;++kc)
        #pragma unroll
        for (int j=0;j<8;++j) pf[qs][kc][j] = (h16)pv[kc*8+j];
    }

    // ---- PV: O^T += V^T · P^T (permuted-k fragments) ----
    #pragma unroll
    for (int kc=0;kc<2;++kc)
      #pragma unroll
      for (int dt=0;dt<4;++dt){
        int vr = dt*16 + (l&15);               // d-row
        int sw = swzkey(vr);
        union { uint2 u2[2]; f16x8 h8; } cv;
        cv.u2[0] = *reinterpret_cast<const uint2*>(VtB + vr*128 + (((kc*4 +     (g>>1)) ^ sw)<<4) + ((g&1)<<3));
        cv.u2[1] = *reinterpret_cast<const uint2*>(VtB + vr*128 + (((kc*4 + 2 + (g>>1)) ^ sw)<<4) + ((g&1)<<3));
        f16x8 vf = cv.h8;
        __builtin_amdgcn_s_setprio(1);
        o[0][dt] = __builtin_amdgcn_mfma_f32_16x16x32_f16(vf, pf[0][kc], o[0][dt], 0,0,0);
        o[1][dt] = __builtin_amdgcn_mfma_f32_16x16x32_f16(vf, pf[1][kc], o[1][dt], 0,0,0);
        __builtin_amdgcn_s_setprio(0);
      }
    cur ^= 1;
  }

  // epilogue: deferred l reduction + store (float4 per dt)
  int b = bh >> 4, hhd = bh & 15;
  #pragma unroll
  for (int qs=0;qs<2;++qs){
    float lt = l_run[qs];
    lt += __shfl_xor(lt, 16);
    lt += __shfl_xor(lt, 32);
    float inv = 1.0f / lt;
    int token = b*SEQ + q0 + qs*16 + (l&15);
    #pragma unroll
    for (int dt=0;dt<4;++dt){
      float4 ov;
      ov.x = o[qs][dt][0]*inv; ov.y = o[qs][dt][1]*inv;
      ov.z = o[qs][dt][2]*inv; ov.w = o[qs][dt][3]*inv;
      *reinterpret_cast<float4*>(att + (size_t)token*DMODEL + hhd*DH + dt*16 + (g<<2)) = ov;
    }
  }
}

// ---------------- launch ----------------
extern "C" void kernel_launch(void* const* d_in, const int* in_sizes, int n_in,
                              void* d_out, int out_size, void* d_ws, size_t ws_size,
                              hipStream_t stream){
  (void)in_sizes; (void)n_in; (void)out_size; (void)ws_size;
  const float* x    = (const float*)d_in[0];
  const float* Wq   = (const float*)d_in[1];
  const float* Wk   = (const float*)d_in[2];
  const float* Wv   = (const float*)d_in[3];
  const float* W1   = (const float*)d_in[4];
  const float* b1   = (const float*)d_in[5];
  const float* W2   = (const float*)d_in[6];
  const float* b2   = (const float*)d_in[7];
  const float* ln1s = (const float*)d_in[8];
  const float* ln1b = (const float*)d_in[9];
  const float* ln2s = (const float*)d_in[10];
  const float* ln2b = (const float*)d_in[11];

  char* ws = (char*)d_ws;
  float* xn_f32  = (float*)ws;  ws += (size_t)NTOK*DMODEL*4;
  float* att_f32 = (float*)ws;  ws += (size_t)NTOK*DMODEL*4;
  float* xt_f32  = (float*)ws;  ws += (size_t)NTOK*DMODEL*4;
  u16* xnh       = (u16*)ws;    ws += (size_t)NTOK*DMODEL*2;
  u16* xnl       = (u16*)ws;    ws += (size_t)NTOK*DMODEL*2;
  h16* qT_h      = (h16*)ws;    ws += (size_t)NTOK*DMODEL*2;
  h16* k_h       = (h16*)ws;    ws += (size_t)NTOK*DMODEL*2;
  h16* vT_h      = (h16*)ws;    ws += (size_t)NTOK*DMODEL*2;
  h16* xt_h      = (h16*)ws;    ws += (size_t)NTOK*DMODEL*2;
  h16* h_h       = (h16*)ws;    ws += (size_t)NTOK*DMODEL*2;
  u16* whi       = (u16*)ws;    ws += (size_t)2*DMODEL*DMODEL*2;
  u16* wlo       = (u16*)ws;    ws += (size_t)2*DMODEL*DMODEL*2;
  u16* wvh       = (u16*)ws;    ws += (size_t)DMODEL*DMODEL*2;
  h16* w1h       = (h16*)ws;    ws += (size_t)DMODEL*DMODEL*2;
  h16* w2h       = (h16*)ws;    ws += (size_t)DMODEL*DMODEL*2;

  prep_weights<<<5120, 256, 0, stream>>>(Wq, Wk, Wv, W1, W2, whi, wlo, wvh, w1h, w2h);

  ln_kernel<<<NTOK/4, 256, 0, stream>>>(x, nullptr, ln1s, ln1b, xn_f32, xnh, xnl, nullptr);

  gemm_qkv<<<dim3(3*DMODEL/128, NTOK/128), 256, 0, stream>>>(
      xnh, xnl, whi, wlo, wvh, qT_h, k_h, vT_h);

  attn_kernel<<<BH*(SEQ/QBLK), 512, 0, stream>>>(qT_h, k_h, vT_h, att_f32);

  ln_kernel<<<NTOK/4, 256, 0, stream>>>(xn_f32, att_f32, ln2s, ln2b, xt_f32, nullptr, nullptr, xt_h);

  gemm_ffn<true,false,false><<<dim3(DMODEL/128, NTOK/128), 256, 0, stream>>>(
      xt_h, w1h, b1, nullptr, h_h, NTOK, DMODEL, DMODEL);

  gemm_ffn<false,true,true><<<dim3(DMODEL/128, NTOK/128), 256, 0, stream>>>(
      h_h, w2h, b2, xt_f32, d_out, NTOK, DMODEL, DMODEL);
}

// Round 8
// 341.491 us; speedup vs baseline: 1.6428x; 1.1756x over previous
//
#include <hip/hip_runtime.h>
#include <stdint.h>

typedef unsigned short u16;
typedef __attribute__((ext_vector_type(4))) float f32x4;
typedef _Float16 h16;
typedef __attribute__((ext_vector_type(8))) _Float16 f16x8;   // 8 x fp16
typedef __attribute__((ext_vector_type(4))) _Float16 h16x4;

#define DMODEL 1024
#define SEQ    2048
#define BATCH  4
#define NHEAD  16
#define DH     64
#define NTOK   (BATCH*SEQ)
#define BH     (BATCH*NHEAD)
#define EPS    1e-5f

__device__ __forceinline__ void gload_lds16(const void* g, void* l){
  __builtin_amdgcn_global_load_lds((__attribute__((address_space(1))) unsigned int*)g,
                                   (__attribute__((address_space(3))) unsigned int*)l,
                                   16, 0, 0);
}

// swizzle key for 128B-row tiles (8 chunks of 16B per row)
__device__ __forceinline__ int swzkey(int row){ return (row&7) ^ ((row>>3)&7); }

// ---------------- weight prep: all five weights -> fp16 ----------------
__global__ __launch_bounds__(256) void prep_weights(const float* __restrict__ Wq,
                                                    const float* __restrict__ Wk,
                                                    const float* __restrict__ Wv,
                                                    const float* __restrict__ W1,
                                                    const float* __restrict__ W2,
                                                    h16* __restrict__ wqkv,
                                                    h16* __restrict__ w1h,
                                                    h16* __restrict__ w2h){
  const int nW = DMODEL*DMODEL;
  int r = blockIdx.x >> 10;
  int i = ((blockIdx.x & 1023)*256 + threadIdx.x)*4;
  const float* src = (r==0) ? Wq : (r==1) ? Wk : (r==2) ? Wv : (r==3) ? W1 : W2;
  h16* dst = (r==0) ? wqkv : (r==1) ? (wqkv+nW) : (r==2) ? (wqkv+2*nW) : (r==3) ? w1h : w2h;
  float4 v = *reinterpret_cast<const float4*>(src + i);
  h16x4 o; o[0]=(h16)v.x; o[1]=(h16)v.y; o[2]=(h16)v.z; o[3]=(h16)v.w;
  *reinterpret_cast<h16x4*>(dst + i) = o;
}

// ---------------- LayerNorm (wave-per-row): f32 (opt) + fp16 (opt) ----------------
__global__ __launch_bounds__(256) void ln_kernel(const float* __restrict__ in0,
                                                 const float* __restrict__ in1,
                                                 const float* __restrict__ sc,
                                                 const float* __restrict__ bi,
                                                 float* __restrict__ of32,
                                                 h16* __restrict__ oh16){
  int row = blockIdx.x*4 + (threadIdx.x>>6);
  int l = threadIdx.x & 63;
  size_t rbase = (size_t)row*DMODEL;
  float v[16];
  #pragma unroll
  for (int q=0;q<4;++q){
    float4 t = *reinterpret_cast<const float4*>(in0 + rbase + q*256 + l*4);
    if (in1){
      float4 a = *reinterpret_cast<const float4*>(in1 + rbase + q*256 + l*4);
      t.x+=a.x; t.y+=a.y; t.z+=a.z; t.w+=a.w;
    }
    v[q*4]=t.x; v[q*4+1]=t.y; v[q*4+2]=t.z; v[q*4+3]=t.w;
  }
  float s=0.f, ss=0.f;
  #pragma unroll
  for (int j=0;j<16;++j){ s += v[j]; ss += v[j]*v[j]; }
  #pragma unroll
  for (int m=1;m<64;m<<=1){ s += __shfl_xor(s,m); ss += __shfl_xor(ss,m); }
  float mu  = s * (1.0f/DMODEL);
  float var = fmaxf(ss * (1.0f/DMODEL) - mu*mu, 0.0f);
  float r = rsqrtf(var + EPS);
  #pragma unroll
  for (int q=0;q<4;++q){
    float4 g = *reinterpret_cast<const float4*>(sc + q*256 + l*4);
    float4 b = *reinterpret_cast<const float4*>(bi + q*256 + l*4);
    float o0 = (v[q*4  ]-mu)*r*g.x + b.x;
    float o1 = (v[q*4+1]-mu)*r*g.y + b.y;
    float o2 = (v[q*4+2]-mu)*r*g.z + b.z;
    float o3 = (v[q*4+3]-mu)*r*g.w + b.w;
    size_t off = rbase + q*256 + l*4;
    if (of32){
      float4 ov; ov.x=o0; ov.y=o1; ov.z=o2; ov.w=o3;
      *reinterpret_cast<float4*>(of32 + off) = ov;
    }
    if (oh16){
      h16x4 oh; oh[0]=(h16)o0; oh[1]=(h16)o1; oh[2]=(h16)o2; oh[3]=(h16)o3;
      *reinterpret_cast<h16x4*>(oh16 + off) = oh;
    }
  }
}

// ---------------- fused QKV GEMM (pure fp16) ----------------
// A = xn fp16 [M][K], W = wqkv fp16 [3072][K]. Outputs fp16:
// qT[bh][64][SEQ], kR[bh][SEQ][64], vT[bh][64][SEQ].
__global__ __launch_bounds__(256) void gemm_qkv(const h16* __restrict__ xn,
                                                const h16* __restrict__ wqkv,
                                                h16* __restrict__ qT,
                                                h16* __restrict__ kR,
                                                h16* __restrict__ vT){
  const int K = DMODEL;
  __shared__ h16 As[128*32], Bs[128*32];
  int t = threadIdx.x, l = t&63, w = t>>6;
  int bm = blockIdx.y, bn = blockIdx.x;
  int wr = w>>1, wc = w&1;
  const h16* Bsrc = wqkv + (size_t)bn*128*K;

  f32x4 acc[4][4];
  #pragma unroll
  for (int m=0;m<4;++m)
    #pragma unroll
    for (int n=0;n<4;++n)
      #pragma unroll
      for (int i=0;i<4;++i) acc[m][n][i] = 0.0f;

  const int nk = K/32;
  for (int kt=0; kt<nk; ++kt){
    int k0 = kt*32;
    __syncthreads();
    #pragma unroll
    for (int i=0;i<2;++i){
      int slot = i*256 + t;
      int row = slot>>2, pc = slot&3;
      int lc = pc ^ (row&3);
      gload_lds16(xn + (size_t)(bm*128 + row)*K + k0 + lc*8, &As[slot*8]);
      gload_lds16(Bsrc + (size_t)row*K + k0 + lc*8, &Bs[slot*8]);
    }
    __syncthreads();
    f16x8 af[4], bf[4];
    #pragma unroll
    for (int m=0;m<4;++m){
      int row = wr*64 + m*16 + (l&15);
      int cp = (l>>4) ^ (row&3);
      af[m] = *reinterpret_cast<const f16x8*>(&As[row*32 + cp*8]);
    }
    #pragma unroll
    for (int n=0;n<4;++n){
      int row = wc*64 + n*16 + (l&15);
      int cp = (l>>4) ^ (row&3);
      bf[n] = *reinterpret_cast<const f16x8*>(&Bs[row*32 + cp*8]);
    }
    __builtin_amdgcn_s_setprio(1);
    #pragma unroll
    for (int m=0;m<4;++m)
      #pragma unroll
      for (int n=0;n<4;++n)
        acc[m][n] = __builtin_amdgcn_mfma_f32_16x16x32_f16(af[m], bf[n], acc[m][n], 0,0,0);
    __builtin_amdgcn_s_setprio(0);
  }

  // epilogue: Q,V transposed vectorized; K row-major scalar
  const bool isK = (bn >= 8 && bn < 16);
  #pragma unroll
  for (int m=0;m<4;++m){
    int row0 = bm*128 + wr*64 + m*16 + ((l>>4)<<2);
    int b = row0 >> 11, s0 = row0 & 2047;
    #pragma unroll
    for (int n=0;n<4;++n){
      int col = bn*128 + wc*64 + n*16 + (l&15);
      int dg = col & 1023;
      int hh = dg >> 6, dh = dg & 63;
      if (isK){
        #pragma unroll
        for (int i=0;i<4;++i)
          kR[((size_t)(b*NHEAD + hh)*SEQ + s0 + i)*DH + dh] = (h16)acc[m][n][i];
      } else {
        h16x4 ov;
        #pragma unroll
        for (int i=0;i<4;++i) ov[i] = (h16)acc[m][n][i];
        h16* dst = ((col < 1024) ? qT : vT) + ((size_t)(b*NHEAD + hh)*DH + dh)*SEQ + s0;
        *reinterpret_cast<h16x4*>(dst) = ov;
      }
    }
  }
}

// ---------------- fp16 GEMM (FFN) ----------------
template<bool RELU, bool RES, bool OUTF32>
__global__ __launch_bounds__(256) void gemm_ffn(const h16* __restrict__ A,
                                                const h16* __restrict__ W,
                                                const float* __restrict__ bias,
                                                const float* __restrict__ resid,
                                                void* __restrict__ outp,
                                                int M, int N, int K){
  __shared__ h16 As[128*32];
  __shared__ h16 Bs[128*32];
  int t = threadIdx.x, l = t&63, w = t>>6;
  int bm = blockIdx.y, bn = blockIdx.x;
  int wr = w>>1, wc = w&1;
  f32x4 acc[4][4];
  #pragma unroll
  for (int m=0;m<4;++m)
    #pragma unroll
    for (int n=0;n<4;++n)
      #pragma unroll
      for (int i=0;i<4;++i) acc[m][n][i] = 0.0f;

  const int nk = K/32;
  for (int kt=0; kt<nk; ++kt){
    int k0 = kt*32;
    __syncthreads();
    #pragma unroll
    for (int i=0;i<2;++i){
      int idx = i*256 + t;
      int r = idx>>2;
      int cc = (idx&3) ^ (r&3);
      gload_lds16(A + (size_t)(bm*128 + r)*K + k0 + cc*8, &As[idx*8]);
      gload_lds16(W + (size_t)(bn*128 + r)*K + k0 + cc*8, &Bs[idx*8]);
    }
    __syncthreads();
    f16x8 af[4], bf[4];
    #pragma unroll
    for (int m=0;m<4;++m){
      int row = wr*64 + m*16 + (l&15);
      int cp = (l>>4) ^ (row&3);
      af[m] = *reinterpret_cast<const f16x8*>(&As[row*32 + cp*8]);
    }
    #pragma unroll
    for (int n=0;n<4;++n){
      int row = wc*64 + n*16 + (l&15);
      int cp = (l>>4) ^ (row&3);
      bf[n] = *reinterpret_cast<const f16x8*>(&Bs[row*32 + cp*8]);
    }
    __builtin_amdgcn_s_setprio(1);
    #pragma unroll
    for (int m=0;m<4;++m)
      #pragma unroll
      for (int n=0;n<4;++n)
        acc[m][n] = __builtin_amdgcn_mfma_f32_16x16x32_f16(af[m], bf[n], acc[m][n], 0,0,0);
    __builtin_amdgcn_s_setprio(0);
  }

  #pragma unroll
  for (int m=0;m<4;++m){
    int row0 = bm*128 + wr*64 + m*16 + ((l>>4)<<2);
    #pragma unroll
    for (int n=0;n<4;++n){
      int col = bn*128 + wc*64 + n*16 + (l&15);
      float bv = bias[col];
      #pragma unroll
      for (int i=0;i<4;++i){
        float vv = acc[m][n][i] + bv;
        if (RELU) vv = fmaxf(vv, 0.0f);
        size_t off = (size_t)(row0+i)*N + col;
        if (RES) vv += resid[off];
        if (OUTF32) ((float*)outp)[off] = vv;
        else        ((h16*)outp)[off] = (h16)vv;
      }
    }
  }
}

// ---------------- flash attention v5: fp16, 8 waves, QBLK=256, defer-max ----------------
#define QBLK 256
#define KBLK 64
#define RESC_THR 8.0f

__global__ __launch_bounds__(512, 2) void attn_kernel(const h16* __restrict__ qT,
                                                      const h16* __restrict__ kR,
                                                      const h16* __restrict__ vT,
                                                      float* __restrict__ att){
  int id = blockIdx.x;                      // XCD-aware decode: same bh -> same id&7
  int bh = (id & 7) + ((id >> 6) << 3);
  int qb = (id >> 3) & 7;
  int t = threadIdx.x, l = t&63, w = t>>6;
  int g = l>>4;

  const size_t hbase = (size_t)bh * SEQ * DH;
  const h16* khb = kR + hbase;              // [s][64]
  const h16* qtb = qT + hbase;              // [64][s]
  const h16* vtb = vT + hbase;              // [64][s]
  int q0 = qb*QBLK + w*32;

  // Q fragments from qT (strided scalar loads, once per block)
  f16x8 qf[2][2];
  #pragma unroll
  for (int qs=0;qs<2;++qs)
    #pragma unroll
    for (int kc=0;kc<2;++kc){
      #pragma unroll
      for (int j=0;j<8;++j)
        qf[qs][kc][j] = qtb[(size_t)(kc*32 + g*8 + j)*SEQ + q0 + qs*16 + (l&15)];
    }

  __shared__ h16 Kh2[2][KBLK*64];
  __shared__ h16 Vt2[2][KBLK*64];

  // O^T accumulators: lane holds q=l&15, d = dt*16 + (l>>4)*4 + i
  f32x4 o[2][4];
  #pragma unroll
  for (int qs=0;qs<2;++qs)
    #pragma unroll
    for (int dt=0;dt<4;++dt)
      #pragma unroll
      for (int i=0;i<4;++i) o[qs][dt][i] = 0.0f;
  float m_run[2] = {-3.0e38f, -3.0e38f};
  float l_run[2] = {0.0f, 0.0f};

  // 512 threads: one 16B chunk per array per tile
  #define STAGE(bb, kt)                                                          \
    { int row_ = t>>3, pc_ = t&7;                                                \
      int lc_ = pc_ ^ swzkey(row_);                                              \
      gload_lds16(khb + ((size_t)((kt)*KBLK + row_))*DH + lc_*8, &Kh2[bb][t*8]); \
      gload_lds16(vtb + (size_t)row_*SEQ + (kt)*KBLK + lc_*8,    &Vt2[bb][t*8]); }

  STAGE(0, 0);
  int cur = 0;
  const int NT = SEQ/KBLK;
  for (int kt=0; kt<NT; ++kt){
    __syncthreads();                 // vmcnt(0)+barrier: staged tile ready
    if (kt+1 < NT) STAGE(cur^1, kt+1);

    char* KhB = (char*)&Kh2[cur][0];
    char* VtB = (char*)&Vt2[cur][0];

    // ---- S^T = K·Q^T (fp16) ----
    f32x4 sc[2][4];
    #pragma unroll
    for (int qs=0;qs<2;++qs)
      #pragma unroll
      for (int st=0;st<4;++st)
        #pragma unroll
        for (int i=0;i<4;++i) sc[qs][st][i] = 0.0f;

    #pragma unroll
    for (int kc=0;kc<2;++kc)
      #pragma unroll
      for (int st=0;st<4;++st){
        int rr = st*16 + (l&15);               // k-row
        int pcK = (kc*4 + g) ^ swzkey(rr);
        f16x8 kf = *reinterpret_cast<const f16x8*>(KhB + rr*128 + pcK*16);
        __builtin_amdgcn_s_setprio(1);
        sc[0][st] = __builtin_amdgcn_mfma_f32_16x16x32_f16(kf, qf[0][kc], sc[0][st], 0,0,0);
        sc[1][st] = __builtin_amdgcn_mfma_f32_16x16x32_f16(kf, qf[1][kc], sc[1][st], 0,0,0);
        __builtin_amdgcn_s_setprio(0);
      }

    // ---- per-lane online softmax (row q = l&15; partners l^16, l^32) ----
    float mt[2];
    #pragma unroll
    for (int qs=0;qs<2;++qs){
      float m0 = sc[qs][0][0];
      #pragma unroll
      for (int st=0;st<4;++st)
        #pragma unroll
        for (int i=0;i<4;++i) m0 = fmaxf(m0, sc[qs][st][i]);
      m0 = fmaxf(m0, __shfl_xor(m0, 16));
      m0 = fmaxf(m0, __shfl_xor(m0, 32));
      mt[qs] = m0;
    }
    bool defer = (__all((mt[0] <= m_run[0] + RESC_THR) &&
                        (mt[1] <= m_run[1] + RESC_THR)) != 0);

    f16x8 pf[2][2];                 // [qs][kc] PV B-fragments
    #pragma unroll
    for (int qs=0;qs<2;++qs){
      float mn = defer ? m_run[qs] : fmaxf(m_run[qs], mt[qs]);
      float pv[16];
      float psum = 0.0f;
      #pragma unroll
      for (int st=0;st<4;++st)
        #pragma unroll
        for (int i=0;i<4;++i){
          float p = __expf(sc[qs][st][i] - mn);
          psum += p;
          pv[st*4+i] = p;
        }
      if (defer){
        l_run[qs] += psum;
      } else {
        float scl = __expf(m_run[qs] - mn);
        m_run[qs] = mn;
        l_run[qs] = l_run[qs]*scl + psum;
        #pragma unroll
        for (int dt=0;dt<4;++dt)
          #pragma unroll
          for (int i=0;i<4;++i) o[qs][dt][i] *= scl;
      }
      #pragma unroll
      for (int kc=0;kc<2;++kc)
        #pragma unroll
        for (int j=0;j<8;++j) pf[qs][kc][j] = (h16)pv[kc*8+j];
    }

    // ---- PV: O^T += V^T · P^T (permuted-k fragments) ----
    #pragma unroll
    for (int kc=0;kc<2;++kc)
      #pragma unroll
      for (int dt=0;dt<4;++dt){
        int vr = dt*16 + (l&15);               // d-row
        int sw = swzkey(vr);
        union { uint2 u2[2]; f16x8 h8; } cv;
        cv.u2[0] = *reinterpret_cast<const uint2*>(VtB + vr*128 + (((kc*4 +     (g>>1)) ^ sw)<<4) + ((g&1)<<3));
        cv.u2[1] = *reinterpret_cast<const uint2*>(VtB + vr*128 + (((kc*4 + 2 + (g>>1)) ^ sw)<<4) + ((g&1)<<3));
        f16x8 vf = cv.h8;
        __builtin_amdgcn_s_setprio(1);
        o[0][dt] = __builtin_amdgcn_mfma_f32_16x16x32_f16(vf, pf[0][kc], o[0][dt], 0,0,0);
        o[1][dt] = __builtin_amdgcn_mfma_f32_16x16x32_f16(vf, pf[1][kc], o[1][dt], 0,0,0);
        __builtin_amdgcn_s_setprio(0);
      }
    cur ^= 1;
  }

  // epilogue: deferred l reduction + store (float4 per dt)
  int b = bh >> 4, hhd = bh & 15;
  #pragma unroll
  for (int qs=0;qs<2;++qs){
    float lt = l_run[qs];
    lt += __shfl_xor(lt, 16);
    lt += __shfl_xor(lt, 32);
    float inv = 1.0f / lt;
    int token = b*SEQ + q0 + qs*16 + (l&15);
    #pragma unroll
    for (int dt=0;dt<4;++dt){
      float4 ov;
      ov.x = o[qs][dt][0]*inv; ov.y = o[qs][dt][1]*inv;
      ov.z = o[qs][dt][2]*inv; ov.w = o[qs][dt][3]*inv;
      *reinterpret_cast<float4*>(att + (size_t)token*DMODEL + hhd*DH + dt*16 + (g<<2)) = ov;
    }
  }
}

// ---------------- launch ----------------
extern "C" void kernel_launch(void* const* d_in, const int* in_sizes, int n_in,
                              void* d_out, int out_size, void* d_ws, size_t ws_size,
                              hipStream_t stream){
  (void)in_sizes; (void)n_in; (void)out_size; (void)ws_size;
  const float* x    = (const float*)d_in[0];
  const float* Wq   = (const float*)d_in[1];
  const float* Wk   = (const float*)d_in[2];
  const float* Wv   = (const float*)d_in[3];
  const float* W1   = (const float*)d_in[4];
  const float* b1   = (const float*)d_in[5];
  const float* W2   = (const float*)d_in[6];
  const float* b2   = (const float*)d_in[7];
  const float* ln1s = (const float*)d_in[8];
  const float* ln1b = (const float*)d_in[9];
  const float* ln2s = (const float*)d_in[10];
  const float* ln2b = (const float*)d_in[11];

  char* ws = (char*)d_ws;
  float* xn_f32  = (float*)ws;  ws += (size_t)NTOK*DMODEL*4;
  float* att_f32 = (float*)ws;  ws += (size_t)NTOK*DMODEL*4;
  float* xt_f32  = (float*)ws;  ws += (size_t)NTOK*DMODEL*4;
  h16* xn_h      = (h16*)ws;    ws += (size_t)NTOK*DMODEL*2;
  h16* qT_h      = (h16*)ws;    ws += (size_t)NTOK*DMODEL*2;
  h16* k_h       = (h16*)ws;    ws += (size_t)NTOK*DMODEL*2;
  h16* vT_h      = (h16*)ws;    ws += (size_t)NTOK*DMODEL*2;
  h16* xt_h      = (h16*)ws;    ws += (size_t)NTOK*DMODEL*2;
  h16* h_h       = (h16*)ws;    ws += (size_t)NTOK*DMODEL*2;
  h16* wqkv_h    = (h16*)ws;    ws += (size_t)3*DMODEL*DMODEL*2;
  h16* w1h       = (h16*)ws;    ws += (size_t)DMODEL*DMODEL*2;
  h16* w2h       = (h16*)ws;    ws += (size_t)DMODEL*DMODEL*2;

  prep_weights<<<5120, 256, 0, stream>>>(Wq, Wk, Wv, W1, W2, wqkv_h, w1h, w2h);

  ln_kernel<<<NTOK/4, 256, 0, stream>>>(x, nullptr, ln1s, ln1b, xn_f32, xn_h);

  gemm_qkv<<<dim3(3*DMODEL/128, NTOK/128), 256, 0, stream>>>(
      xn_h, wqkv_h, qT_h, k_h, vT_h);

  attn_kernel<<<BH*(SEQ/QBLK), 512, 0, stream>>>(qT_h, k_h, vT_h, att_f32);

  ln_kernel<<<NTOK/4, 256, 0, stream>>>(xn_f32, att_f32, ln2s, ln2b, xt_f32, xt_h);

  gemm_ffn<true,false,false><<<dim3(DMODEL/128, NTOK/128), 256, 0, stream>>>(
      xt_h, w1h, b1, nullptr, h_h, NTOK, DMODEL, DMODEL);

  gemm_ffn<false,true,true><<<dim3(DMODEL/128, NTOK/128), 256, 0, stream>>>(
      h_h, w2h, b2, xt_f32, d_out, NTOK, DMODEL, DMODEL);
}

// Round 9
// 336.755 us; speedup vs baseline: 1.6659x; 1.0141x over previous
//
#include <hip/hip_runtime.h>
#include <stdint.h>

typedef unsigned short u16;
typedef __attribute__((ext_vector_type(4))) float f32x4;
typedef _Float16 h16;
typedef __attribute__((ext_vector_type(8))) _Float16 f16x8;   // 8 x fp16
typedef __attribute__((ext_vector_type(4))) _Float16 h16x4;

#define DMODEL 1024
#define SEQ    2048
#define BATCH  4
#define NHEAD  16
#define DH     64
#define NTOK   (BATCH*SEQ)
#define BH     (BATCH*NHEAD)
#define EPS    1e-5f
#define LOG2E  1.44269504f

__device__ __forceinline__ void gload_lds16(const void* g, void* l){
  __builtin_amdgcn_global_load_lds((__attribute__((address_space(1))) unsigned int*)g,
                                   (__attribute__((address_space(3))) unsigned int*)l,
                                   16, 0, 0);
}

// swizzle key for 128B-row tiles (8 chunks of 16B per row)
__device__ __forceinline__ int swzkey(int row){ return (row&7) ^ ((row>>3)&7); }

// ---------------- weight prep: all five weights -> fp16 ----------------
__global__ __launch_bounds__(256) void prep_weights(const float* __restrict__ Wq,
                                                    const float* __restrict__ Wk,
                                                    const float* __restrict__ Wv,
                                                    const float* __restrict__ W1,
                                                    const float* __restrict__ W2,
                                                    h16* __restrict__ wqkv,
                                                    h16* __restrict__ w1h,
                                                    h16* __restrict__ w2h){
  const int nW = DMODEL*DMODEL;
  int r = blockIdx.x >> 10;
  int i = ((blockIdx.x & 1023)*256 + threadIdx.x)*4;
  const float* src = (r==0) ? Wq : (r==1) ? Wk : (r==2) ? Wv : (r==3) ? W1 : W2;
  h16* dst = (r==0) ? wqkv : (r==1) ? (wqkv+nW) : (r==2) ? (wqkv+2*nW) : (r==3) ? w1h : w2h;
  float4 v = *reinterpret_cast<const float4*>(src + i);
  h16x4 o; o[0]=(h16)v.x; o[1]=(h16)v.y; o[2]=(h16)v.z; o[3]=(h16)v.w;
  *reinterpret_cast<h16x4*>(dst + i) = o;
}

// ---------------- LayerNorm (wave-per-row): f32 (opt) + fp16 (opt) ----------------
__global__ __launch_bounds__(256) void ln_kernel(const float* __restrict__ in0,
                                                 const float* __restrict__ in1,
                                                 const float* __restrict__ sc,
                                                 const float* __restrict__ bi,
                                                 float* __restrict__ of32,
                                                 h16* __restrict__ oh16){
  int row = blockIdx.x*4 + (threadIdx.x>>6);
  int l = threadIdx.x & 63;
  size_t rbase = (size_t)row*DMODEL;
  float v[16];
  #pragma unroll
  for (int q=0;q<4;++q){
    float4 t = *reinterpret_cast<const float4*>(in0 + rbase + q*256 + l*4);
    if (in1){
      float4 a = *reinterpret_cast<const float4*>(in1 + rbase + q*256 + l*4);
      t.x+=a.x; t.y+=a.y; t.z+=a.z; t.w+=a.w;
    }
    v[q*4]=t.x; v[q*4+1]=t.y; v[q*4+2]=t.z; v[q*4+3]=t.w;
  }
  float s=0.f, ss=0.f;
  #pragma unroll
  for (int j=0;j<16;++j){ s += v[j]; ss += v[j]*v[j]; }
  #pragma unroll
  for (int m=1;m<64;m<<=1){ s += __shfl_xor(s,m); ss += __shfl_xor(ss,m); }
  float mu  = s * (1.0f/DMODEL);
  float var = fmaxf(ss * (1.0f/DMODEL) - mu*mu, 0.0f);
  float r = rsqrtf(var + EPS);
  #pragma unroll
  for (int q=0;q<4;++q){
    float4 g = *reinterpret_cast<const float4*>(sc + q*256 + l*4);
    float4 b = *reinterpret_cast<const float4*>(bi + q*256 + l*4);
    float o0 = (v[q*4  ]-mu)*r*g.x + b.x;
    float o1 = (v[q*4+1]-mu)*r*g.y + b.y;
    float o2 = (v[q*4+2]-mu)*r*g.z + b.z;
    float o3 = (v[q*4+3]-mu)*r*g.w + b.w;
    size_t off = rbase + q*256 + l*4;
    if (of32){
      float4 ov; ov.x=o0; ov.y=o1; ov.z=o2; ov.w=o3;
      *reinterpret_cast<float4*>(of32 + off) = ov;
    }
    if (oh16){
      h16x4 oh; oh[0]=(h16)o0; oh[1]=(h16)o1; oh[2]=(h16)o2; oh[3]=(h16)o3;
      *reinterpret_cast<h16x4*>(oh16 + off) = oh;
    }
  }
}

// ---------------- fused QKV GEMM (pure fp16) ----------------
// Outputs: qT[bh][64][SEQ] scaled by log2(e); kR[bh][SEQ][64];
// vT[bh][64][SEQ] with sigma-permuted s within each 32-group so the PV
// A-fragment is one contiguous ds_read_b128 (perm applied consistently to
// P's k-order in attn -> numerically exact).
__global__ __launch_bounds__(256) void gemm_qkv(const h16* __restrict__ xn,
                                                const h16* __restrict__ wqkv,
                                                h16* __restrict__ qT,
                                                h16* __restrict__ kR,
                                                h16* __restrict__ vT){
  const int K = DMODEL;
  __shared__ h16 As[128*32], Bs[128*32];
  int t = threadIdx.x, l = t&63, w = t>>6;
  int bm = blockIdx.y, bn = blockIdx.x;
  int wr = w>>1, wc = w&1;
  const h16* Bsrc = wqkv + (size_t)bn*128*K;

  f32x4 acc[4][4];
  #pragma unroll
  for (int m=0;m<4;++m)
    #pragma unroll
    for (int n=0;n<4;++n)
      #pragma unroll
      for (int i=0;i<4;++i) acc[m][n][i] = 0.0f;

  const int nk = K/32;
  for (int kt=0; kt<nk; ++kt){
    int k0 = kt*32;
    __syncthreads();
    #pragma unroll
    for (int i=0;i<2;++i){
      int slot = i*256 + t;
      int row = slot>>2, pc = slot&3;
      int lc = pc ^ (row&3);
      gload_lds16(xn + (size_t)(bm*128 + row)*K + k0 + lc*8, &As[slot*8]);
      gload_lds16(Bsrc + (size_t)row*K + k0 + lc*8, &Bs[slot*8]);
    }
    __syncthreads();
    f16x8 af[4], bf[4];
    #pragma unroll
    for (int m=0;m<4;++m){
      int row = wr*64 + m*16 + (l&15);
      int cp = (l>>4) ^ (row&3);
      af[m] = *reinterpret_cast<const f16x8*>(&As[row*32 + cp*8]);
    }
    #pragma unroll
    for (int n=0;n<4;++n){
      int row = wc*64 + n*16 + (l&15);
      int cp = (l>>4) ^ (row&3);
      bf[n] = *reinterpret_cast<const f16x8*>(&Bs[row*32 + cp*8]);
    }
    __builtin_amdgcn_s_setprio(1);
    #pragma unroll
    for (int m=0;m<4;++m)
      #pragma unroll
      for (int n=0;n<4;++n)
        acc[m][n] = __builtin_amdgcn_mfma_f32_16x16x32_f16(af[m], bf[n], acc[m][n], 0,0,0);
    __builtin_amdgcn_s_setprio(0);
  }

  // epilogue
  const bool isK = (bn >= 8 && bn < 16);
  const bool isQ = (bn < 8);
  #pragma unroll
  for (int m=0;m<4;++m){
    int row0 = bm*128 + wr*64 + m*16 + ((l>>4)<<2);
    int b = row0 >> 11, s0 = row0 & 2047;
    #pragma unroll
    for (int n=0;n<4;++n){
      int col = bn*128 + wc*64 + n*16 + (l&15);
      int dg = col & 1023;
      int hh = dg >> 6, dh = dg & 63;
      if (isK){
        #pragma unroll
        for (int i=0;i<4;++i)
          kR[((size_t)(b*NHEAD + hh)*SEQ + s0 + i)*DH + dh] = (h16)acc[m][n][i];
      } else {
        h16x4 ov;
        #pragma unroll
        for (int i=0;i<4;++i){
          float vv = acc[m][n][i];
          if (isQ) vv *= LOG2E;
          ov[i] = (h16)vv;
        }
        // sigma-permute s for V: within 32-group, pos = (c&3) + (c>>2)*8 + h*4
        int s0p = isQ ? s0 : ((s0 & ~31) + (((s0>>2)&3)<<3) + (((s0>>4)&1)<<2));
        h16* dst = (isQ ? qT : vT) + ((size_t)(b*NHEAD + hh)*DH + dh)*SEQ + s0p;
        *reinterpret_cast<h16x4*>(dst) = ov;
      }
    }
  }
}

// ---------------- fp16 GEMM (FFN) ----------------
template<bool RELU, bool RES, bool OUTF32>
__global__ __launch_bounds__(256) void gemm_ffn(const h16* __restrict__ A,
                                                const h16* __restrict__ W,
                                                const float* __restrict__ bias,
                                                const float* __restrict__ resid,
                                                void* __restrict__ outp,
                                                int M, int N, int K){
  __shared__ h16 As[128*32];
  __shared__ h16 Bs[128*32];
  int t = threadIdx.x, l = t&63, w = t>>6;
  int bm = blockIdx.y, bn = blockIdx.x;
  int wr = w>>1, wc = w&1;
  f32x4 acc[4][4];
  #pragma unroll
  for (int m=0;m<4;++m)
    #pragma unroll
    for (int n=0;n<4;++n)
      #pragma unroll
      for (int i=0;i<4;++i) acc[m][n][i] = 0.0f;

  const int nk = K/32;
  for (int kt=0; kt<nk; ++kt){
    int k0 = kt*32;
    __syncthreads();
    #pragma unroll
    for (int i=0;i<2;++i){
      int idx = i*256 + t;
      int r = idx>>2;
      int cc = (idx&3) ^ (r&3);
      gload_lds16(A + (size_t)(bm*128 + r)*K + k0 + cc*8, &As[idx*8]);
      gload_lds16(W + (size_t)(bn*128 + r)*K + k0 + cc*8, &Bs[idx*8]);
    }
    __syncthreads();
    f16x8 af[4], bf[4];
    #pragma unroll
    for (int m=0;m<4;++m){
      int row = wr*64 + m*16 + (l&15);
      int cp = (l>>4) ^ (row&3);
      af[m] = *reinterpret_cast<const f16x8*>(&As[row*32 + cp*8]);
    }
    #pragma unroll
    for (int n=0;n<4;++n){
      int row = wc*64 + n*16 + (l&15);
      int cp = (l>>4) ^ (row&3);
      bf[n] = *reinterpret_cast<const f16x8*>(&Bs[row*32 + cp*8]);
    }
    __builtin_amdgcn_s_setprio(1);
    #pragma unroll
    for (int m=0;m<4;++m)
      #pragma unroll
      for (int n=0;n<4;++n)
        acc[m][n] = __builtin_amdgcn_mfma_f32_16x16x32_f16(af[m], bf[n], acc[m][n], 0,0,0);
    __builtin_amdgcn_s_setprio(0);
  }

  #pragma unroll
  for (int m=0;m<4;++m){
    int row0 = bm*128 + wr*64 + m*16 + ((l>>4)<<2);
    #pragma unroll
    for (int n=0;n<4;++n){
      int col = bn*128 + wc*64 + n*16 + (l&15);
      float bv = bias[col];
      #pragma unroll
      for (int i=0;i<4;++i){
        float vv = acc[m][n][i] + bv;
        if (RELU) vv = fmaxf(vv, 0.0f);
        size_t off = (size_t)(row0+i)*N + col;
        if (RES) vv += resid[off];
        if (OUTF32) ((float*)outp)[off] = vv;
        else        ((h16*)outp)[off] = (h16)vv;
      }
    }
  }
}

// ---------------- flash attention v6: fp16, 8 waves x 16 q-rows, QBLK=128 ----------------
// log2-domain softmax (q pre-scaled by log2e); sigma-permuted V -> PV single b128 reads.
#define QBLK 128
#define KBLK 64
#define RESC_THR_L2 11.5415603f    // 8 * log2(e)

__global__ __launch_bounds__(512) void attn_kernel(const h16* __restrict__ qT,
                                                   const h16* __restrict__ kR,
                                                   const h16* __restrict__ vT,
                                                   float* __restrict__ att){
  int id = blockIdx.x;                      // XCD-aware decode: same bh stays on one XCD
  int bh = (id & 7) + ((id >> 7) << 3);
  int qb = (id >> 3) & 15;
  int t = threadIdx.x, l = t&63, w = t>>6;
  int g = l>>4;

  const size_t hbase = (size_t)bh * SEQ * DH;
  const h16* khb = kR + hbase;              // [s][64]
  const h16* qtb = qT + hbase;              // [64][s]
  const h16* vtb = vT + hbase;              // [64][s] (sigma-permuted s)
  int q0 = qb*QBLK + w*16;

  // Q fragment (B-operand), log2e-scaled: lane l&15 = q, k-chunk g*8
  f16x8 qf[2];
  #pragma unroll
  for (int kc=0;kc<2;++kc)
    #pragma unroll
    for (int j=0;j<8;++j)
      qf[kc][j] = qtb[(size_t)(kc*32 + g*8 + j)*SEQ + q0 + (l&15)];

  __shared__ h16 Kh2[2][KBLK*64];
  __shared__ h16 Vt2[2][KBLK*64];

  // O^T accumulators: lane holds q=l&15, d = dt*16 + g*4 + i
  f32x4 o[4];
  #pragma unroll
  for (int dt=0;dt<4;++dt)
    #pragma unroll
    for (int i=0;i<4;++i) o[dt][i] = 0.0f;
  float m_run = -3.0e38f;
  float l_run = 0.0f;

  // 512 threads: one 16B chunk per array per tile
  #define STAGE(bb, kt)                                                          \
    { int row_ = t>>3, pc_ = t&7;                                                \
      int lc_ = pc_ ^ swzkey(row_);                                              \
      gload_lds16(khb + ((size_t)((kt)*KBLK + row_))*DH + lc_*8, &Kh2[bb][t*8]); \
      gload_lds16(vtb + (size_t)row_*SEQ + (kt)*KBLK + lc_*8,    &Vt2[bb][t*8]); }

  STAGE(0, 0);
  int cur = 0;
  const int NT = SEQ/KBLK;
  for (int kt=0; kt<NT; ++kt){
    __syncthreads();                 // vmcnt(0)+barrier: staged tile ready
    if (kt+1 < NT) STAGE(cur^1, kt+1);

    char* KhB = (char*)&Kh2[cur][0];
    char* VtB = (char*)&Vt2[cur][0];

    // ---- S^T = K.Q^T (fp16, log2 domain) ----
    f32x4 sc[4];
    #pragma unroll
    for (int st=0;st<4;++st)
      #pragma unroll
      for (int i=0;i<4;++i) sc[st][i] = 0.0f;

    #pragma unroll
    for (int kc=0;kc<2;++kc)
      #pragma unroll
      for (int st=0;st<4;++st){
        int rr = st*16 + (l&15);               // k-row
        int pcK = (kc*4 + g) ^ swzkey(rr);
        f16x8 kf = *reinterpret_cast<const f16x8*>(KhB + rr*128 + pcK*16);
        __builtin_amdgcn_s_setprio(1);
        sc[st] = __builtin_amdgcn_mfma_f32_16x16x32_f16(kf, qf[kc], sc[st], 0,0,0);
        __builtin_amdgcn_s_setprio(0);
      }

    // ---- per-lane online softmax in log2 domain (partners l^16, l^32) ----
    float m0 = sc[0][0];
    #pragma unroll
    for (int st=0;st<4;++st)
      #pragma unroll
      for (int i=0;i<4;++i) m0 = fmaxf(m0, sc[st][i]);
    m0 = fmaxf(m0, __shfl_xor(m0, 16));
    m0 = fmaxf(m0, __shfl_xor(m0, 32));
    bool defer = (__all(m0 <= m_run + RESC_THR_L2) != 0);

    float mn = defer ? m_run : fmaxf(m_run, m0);
    f16x8 pf[2];
    float psum = 0.0f;
    #pragma unroll
    for (int st=0;st<4;++st)
      #pragma unroll
      for (int i=0;i<4;++i){
        float p = exp2f(sc[st][i] - mn);
        psum += p;
        pf[st>>1][((st&1)<<2)+i] = (h16)p;
      }
    if (defer){
      l_run += psum;
    } else {
      float scl = exp2f(m_run - mn);
      m_run = mn;
      l_run = l_run*scl + psum;
      #pragma unroll
      for (int dt=0;dt<4;++dt)
        #pragma unroll
        for (int i=0;i<4;++i) o[dt][i] *= scl;
    }

    // ---- PV: O^T += V^T . P^T (sigma-matched single b128 reads) ----
    #pragma unroll
    for (int kc=0;kc<2;++kc)
      #pragma unroll
      for (int dt=0;dt<4;++dt){
        int vr = dt*16 + (l&15);               // d-row
        int pcV = (kc*4 + g) ^ swzkey(vr);
        f16x8 vf = *reinterpret_cast<const f16x8*>(VtB + vr*128 + pcV*16);
        __builtin_amdgcn_s_setprio(1);
        o[dt] = __builtin_amdgcn_mfma_f32_16x16x32_f16(vf, pf[kc], o[dt], 0,0,0);
        __builtin_amdgcn_s_setprio(0);
      }
    cur ^= 1;
  }

  // epilogue: deferred l reduction + store (float4 per dt)
  int b = bh >> 4, hhd = bh & 15;
  float lt = l_run;
  lt += __shfl_xor(lt, 16);
  lt += __shfl_xor(lt, 32);
  float inv = 1.0f / lt;
  int token = b*SEQ + q0 + (l&15);
  #pragma unroll
  for (int dt=0;dt<4;++dt){
    float4 ov;
    ov.x = o[dt][0]*inv; ov.y = o[dt][1]*inv;
    ov.z = o[dt][2]*inv; ov.w = o[dt][3]*inv;
    *reinterpret_cast<float4*>(att + (size_t)token*DMODEL + hhd*DH + dt*16 + (g<<2)) = ov;
  }
}

// ---------------- launch ----------------
extern "C" void kernel_launch(void* const* d_in, const int* in_sizes, int n_in,
                              void* d_out, int out_size, void* d_ws, size_t ws_size,
                              hipStream_t stream){
  (void)in_sizes; (void)n_in; (void)out_size; (void)ws_size;
  const float* x    = (const float*)d_in[0];
  const float* Wq   = (const float*)d_in[1];
  const float* Wk   = (const float*)d_in[2];
  const float* Wv   = (const float*)d_in[3];
  const float* W1   = (const float*)d_in[4];
  const float* b1   = (const float*)d_in[5];
  const float* W2   = (const float*)d_in[6];
  const float* b2   = (const float*)d_in[7];
  const float* ln1s = (const float*)d_in[8];
  const float* ln1b = (const float*)d_in[9];
  const float* ln2s = (const float*)d_in[10];
  const float* ln2b = (const float*)d_in[11];

  char* ws = (char*)d_ws;
  float* xn_f32  = (float*)ws;  ws += (size_t)NTOK*DMODEL*4;
  float* att_f32 = (float*)ws;  ws += (size_t)NTOK*DMODEL*4;
  float* xt_f32  = (float*)ws;  ws += (size_t)NTOK*DMODEL*4;
  h16* xn_h      = (h16*)ws;    ws += (size_t)NTOK*DMODEL*2;
  h16* qT_h      = (h16*)ws;    ws += (size_t)NTOK*DMODEL*2;
  h16* k_h       = (h16*)ws;    ws += (size_t)NTOK*DMODEL*2;
  h16* vT_h      = (h16*)ws;    ws += (size_t)NTOK*DMODEL*2;
  h16* xt_h      = (h16*)ws;    ws += (size_t)NTOK*DMODEL*2;
  h16* h_h       = (h16*)ws;    ws += (size_t)NTOK*DMODEL*2;
  h16* wqkv_h    = (h16*)ws;    ws += (size_t)3*DMODEL*DMODEL*2;
  h16* w1h       = (h16*)ws;    ws += (size_t)DMODEL*DMODEL*2;
  h16* w2h       = (h16*)ws;    ws += (size_t)DMODEL*DMODEL*2;

  prep_weights<<<5120, 256, 0, stream>>>(Wq, Wk, Wv, W1, W2, wqkv_h, w1h, w2h);

  ln_kernel<<<NTOK/4, 256, 0, stream>>>(x, nullptr, ln1s, ln1b, xn_f32, xn_h);

  gemm_qkv<<<dim3(3*DMODEL/128, NTOK/128), 256, 0, stream>>>(
      xn_h, wqkv_h, qT_h, k_h, vT_h);

  attn_kernel<<<BH*(SEQ/QBLK), 512, 0, stream>>>(qT_h, k_h, vT_h, att_f32);

  ln_kernel<<<NTOK/4, 256, 0, stream>>>(xn_f32, att_f32, ln2s, ln2b, xt_f32, xt_h);

  gemm_ffn<true,false,false><<<dim3(DMODEL/128, NTOK/128), 256, 0, stream>>>(
      xt_h, w1h, b1, nullptr, h_h, NTOK, DMODEL, DMODEL);

  gemm_ffn<false,true,true><<<dim3(DMODEL/128, NTOK/128), 256, 0, stream>>>(
      h_h, w2h, b2, xt_f32, d_out, NTOK, DMODEL, DMODEL);
}